// Round 2
// baseline (995.459 us; speedup 1.0000x reference)
//
#include <hip/hip_runtime.h>

#define B_  16
#define C_  512
#define N_  1024
#define NH  4
#define DK  128
#define M3  1536   // 3*C

// ---------------------------------------------------------------------------
// Kernel 1: QKV projection.
// qkv[b,n,m] = sum_c x[b,c,n] * w_proj[c,m] + b_proj[m]
// x is (B,C,N) so A^T ([c][n]) is the natural layout -> transpose-free staging.
// Output scattered to Q/K/V as [b][h][n][d]; each 128-col tile lies in exactly
// one (h, q/k/v) segment because 3*d_k = 384 = 3*128.
// Tile 128(tokens) x 128(m), 256 threads, 8x8 micro-tile, K-chunk 16.
// ---------------------------------------------------------------------------
__global__ __launch_bounds__(256) void qkv_proj_kernel(
    const float* __restrict__ x, const float* __restrict__ wp,
    const float* __restrict__ bp, float* __restrict__ Q,
    float* __restrict__ K, float* __restrict__ V)
{
    __shared__ float As[16][132];   // As[c][token]  (pitch 132: 528B, 16B-aligned rows)
    __shared__ float Bs[16][132];   // Bs[c][m]

    const int bx = blockIdx.x;            // m tile: 0..11
    const int by = blockIdx.y;            // token tile: 0..7
    const int b  = blockIdx.z;
    const int col0 = bx * 128, row0 = by * 128;
    const int tid = threadIdx.x;
    const int tc = tid & 15, tr = tid >> 4;

    // staging indices: thread covers 8 consecutive floats of each buffer
    const int sc = tid >> 4;              // 0..15 (k row)
    const int sn = (tid & 15) * 8;        // 0..120

    const float* xg = x  + ((size_t)b * C_ + sc) * N_ + row0 + sn;
    const float* wg = wp + (size_t)sc * M3 + col0 + sn;

    float acc[8][8] = {};

    for (int k0 = 0; k0 < C_; k0 += 16) {
        __syncthreads();
        float4 xa0 = *(const float4*)(xg + (size_t)k0 * N_);
        float4 xa1 = *(const float4*)(xg + (size_t)k0 * N_ + 4);
        float4 wb0 = *(const float4*)(wg + (size_t)k0 * M3);
        float4 wb1 = *(const float4*)(wg + (size_t)k0 * M3 + 4);
        *(float4*)&As[sc][sn]     = xa0;
        *(float4*)&As[sc][sn + 4] = xa1;
        *(float4*)&Bs[sc][sn]     = wb0;
        *(float4*)&Bs[sc][sn + 4] = wb1;
        __syncthreads();

#pragma unroll
        for (int kk = 0; kk < 16; ++kk) {
            float4 a0 = *(const float4*)&As[kk][tr * 8];
            float4 a1 = *(const float4*)&As[kk][tr * 8 + 4];
            float4 b0 = *(const float4*)&Bs[kk][tc * 8];
            float4 b1 = *(const float4*)&Bs[kk][tc * 8 + 4];
            float av[8] = {a0.x, a0.y, a0.z, a0.w, a1.x, a1.y, a1.z, a1.w};
            float bv[8] = {b0.x, b0.y, b0.z, b0.w, b1.x, b1.y, b1.z, b1.w};
#pragma unroll
            for (int i = 0; i < 8; ++i)
#pragma unroll
                for (int j = 0; j < 8; ++j)
                    acc[i][j] += av[i] * bv[j];
        }
    }

    // epilogue: route this 128-col block to Q/K/V
    const int seg = bx;                 // = col0/128
    const int h = seg / 3, t = seg % 3;
    float* dst = (t == 0 ? Q : (t == 1 ? K : V));
    dst += ((size_t)(b * NH + h) * N_ + row0 + tr * 8) * DK + tc * 8;

    float4 bi0 = *(const float4*)(bp + col0 + tc * 8);
    float4 bi1 = *(const float4*)(bp + col0 + tc * 8 + 4);

#pragma unroll
    for (int i = 0; i < 8; ++i) {
        float4 o0 = make_float4(acc[i][0] + bi0.x, acc[i][1] + bi0.y,
                                acc[i][2] + bi0.z, acc[i][3] + bi0.w);
        float4 o1 = make_float4(acc[i][4] + bi1.x, acc[i][5] + bi1.y,
                                acc[i][6] + bi1.z, acc[i][7] + bi1.w);
        *(float4*)(dst + (size_t)i * DK)     = o0;
        *(float4*)(dst + (size_t)i * DK + 4) = o1;
    }
}

// ---------------------------------------------------------------------------
// Kernel 2: flash attention per (b,h), 64 q-rows per block, 256 threads.
// Q staged transposed + prescaled once (Qt[d][i]); K staged transposed in
// 64-d chunks; S-GEMM 4x4 micro; online softmax via shfl over 16-lane row
// groups; P through LDS (transposed) -> PV GEMM 4x8 micro, V from global (L2).
// LDS: 34+17+17 = 68KB -> 2 blocks/CU.
// ---------------------------------------------------------------------------
__global__ __launch_bounds__(256) void attn_kernel(
    const float* __restrict__ Q, const float* __restrict__ K,
    const float* __restrict__ V, float* __restrict__ RES)
{
    __shared__ float Qt[128][68];   // Qt[d][i], pitch 68 (272B, 16B aligned)
    __shared__ float Kt[64][68];    // Kt[dd][j] for current 64-d chunk
    __shared__ float Ps[64][68];    // Ps[j][i]

    const int bh = blockIdx.y;            // 0..63
    const int i0 = blockIdx.x * 64;
    const int b  = bh >> 2, h = bh & 3;
    const int tid = threadIdx.x;
    const int tc = tid & 15, tr = tid >> 4;
    const float scale = 0.08838834764831845f;  // 128^-0.5

    const float* Qg = Q + ((size_t)bh * N_ + i0) * DK;
    const float* Kg = K + (size_t)bh * N_ * DK;
    const float* Vg = V + (size_t)bh * N_ * DK;

    // stage Q transposed, prescaled (once)
    {
        const int i = tid >> 2, d0 = (tid & 3) * 32;
        const float* qp = Qg + (size_t)i * DK + d0;
#pragma unroll
        for (int u = 0; u < 32; u += 4) {
            float4 v4 = *(const float4*)(qp + u);
            Qt[d0 + u + 0][i] = v4.x * scale;
            Qt[d0 + u + 1][i] = v4.y * scale;
            Qt[d0 + u + 2][i] = v4.z * scale;
            Qt[d0 + u + 3][i] = v4.w * scale;
        }
    }

    float m_i[4], l_i[4], o_acc[4][8];
#pragma unroll
    for (int ii = 0; ii < 4; ++ii) {
        m_i[ii] = -1e30f;
        l_i[ii] = 0.f;
#pragma unroll
        for (int dd = 0; dd < 8; ++dd) o_acc[ii][dd] = 0.f;
    }

    for (int j0 = 0; j0 < N_; j0 += 64) {
        float s[4][4] = {};

#pragma unroll
        for (int dc = 0; dc < 128; dc += 64) {
            __syncthreads();   // previous users of Kt (and Ps on loop-back) done
            {
                const int j = tid >> 2, dd0 = (tid & 3) * 16;
                const float* kp = Kg + (size_t)(j0 + j) * DK + dc + dd0;
#pragma unroll
                for (int u = 0; u < 16; u += 4) {
                    float4 v4 = *(const float4*)(kp + u);
                    Kt[dd0 + u + 0][j] = v4.x;
                    Kt[dd0 + u + 1][j] = v4.y;
                    Kt[dd0 + u + 2][j] = v4.z;
                    Kt[dd0 + u + 3][j] = v4.w;
                }
            }
            __syncthreads();

#pragma unroll 16
            for (int kk = 0; kk < 64; ++kk) {
                float4 a4 = *(const float4*)&Qt[dc + kk][tr * 4];
                float4 b4 = *(const float4*)&Kt[kk][tc * 4];
                float av[4] = {a4.x, a4.y, a4.z, a4.w};
                float bv[4] = {b4.x, b4.y, b4.z, b4.w};
#pragma unroll
                for (int ii = 0; ii < 4; ++ii)
#pragma unroll
                    for (int jj = 0; jj < 4; ++jj)
                        s[ii][jj] += av[ii] * bv[jj];
            }
        }

        // online softmax (scores already scaled via Q)
#pragma unroll
        for (int ii = 0; ii < 4; ++ii) {
            float rm = fmaxf(fmaxf(s[ii][0], s[ii][1]), fmaxf(s[ii][2], s[ii][3]));
            rm = fmaxf(rm, __shfl_xor(rm, 1));
            rm = fmaxf(rm, __shfl_xor(rm, 2));
            rm = fmaxf(rm, __shfl_xor(rm, 4));
            rm = fmaxf(rm, __shfl_xor(rm, 8));
            float mn = fmaxf(m_i[ii], rm);
            float al = __expf(m_i[ii] - mn);
            m_i[ii] = mn;
            float rs = 0.f;
#pragma unroll
            for (int jj = 0; jj < 4; ++jj) {
                s[ii][jj] = __expf(s[ii][jj] - mn);
                rs += s[ii][jj];
            }
            rs += __shfl_xor(rs, 1);
            rs += __shfl_xor(rs, 2);
            rs += __shfl_xor(rs, 4);
            rs += __shfl_xor(rs, 8);
            l_i[ii] = l_i[ii] * al + rs;
#pragma unroll
            for (int dd = 0; dd < 8; ++dd) o_acc[ii][dd] *= al;
        }

        // P -> LDS transposed (safe: >=2 barriers since last Ps read)
#pragma unroll
        for (int ii = 0; ii < 4; ++ii)
#pragma unroll
            for (int jj = 0; jj < 4; ++jj)
                Ps[tc * 4 + jj][tr * 4 + ii] = s[ii][jj];
        __syncthreads();

        // PV: o[i][d] += P[i][j] * V[j][d], V straight from global (L2-resident)
        const float* vg = Vg + (size_t)j0 * DK + tc * 8;
#pragma unroll 8
        for (int j = 0; j < 64; ++j) {
            float4 p4 = *(const float4*)&Ps[j][tr * 4];
            float4 v0 = *(const float4*)(vg + (size_t)j * DK);
            float4 v1 = *(const float4*)(vg + (size_t)j * DK + 4);
            float pv[4] = {p4.x, p4.y, p4.z, p4.w};
            float vv[8] = {v0.x, v0.y, v0.z, v0.w, v1.x, v1.y, v1.z, v1.w};
#pragma unroll
            for (int ii = 0; ii < 4; ++ii)
#pragma unroll
                for (int dd = 0; dd < 8; ++dd)
                    o_acc[ii][dd] += pv[ii] * vv[dd];
        }
    }

    // epilogue: res[b][n][h*128 + d] = o/l
    float* rp = RES + ((size_t)b * N_ + i0 + tr * 4) * C_ + h * DK + tc * 8;
#pragma unroll
    for (int ii = 0; ii < 4; ++ii) {
        float inv = 1.f / l_i[ii];
        float4 o0 = make_float4(o_acc[ii][0] * inv, o_acc[ii][1] * inv,
                                o_acc[ii][2] * inv, o_acc[ii][3] * inv);
        float4 o1 = make_float4(o_acc[ii][4] * inv, o_acc[ii][5] * inv,
                                o_acc[ii][6] * inv, o_acc[ii][7] * inv);
        *(float4*)(rp + (size_t)ii * C_)     = o0;
        *(float4*)(rp + (size_t)ii * C_ + 4) = o1;
    }
}

// ---------------------------------------------------------------------------
// Kernel 3: out projection + bias + residual, computing C^T directly:
// out[b][c'][n] = sum_c w_out[c][c'] * res[b][n][c] + b_out[c'] + x[b][c'][n]
// Rows = c' (M=512), cols = n (N=1024) -> coalesced stores into (B,C,H,W).
// A-stage from w_out is natural; B-stage transposes res on the fly.
// ---------------------------------------------------------------------------
__global__ __launch_bounds__(256) void out_proj_kernel(
    const float* __restrict__ RES, const float* __restrict__ wo,
    const float* __restrict__ bo, const float* __restrict__ x,
    float* __restrict__ out)
{
    __shared__ float As[16][132];   // As[ck][c']
    __shared__ float Bs[16][132];   // Bs[ck][n]

    const int bx = blockIdx.x;            // c' tile: 0..3
    const int by = blockIdx.y;            // n tile: 0..7
    const int b  = blockIdx.z;
    const int c0 = bx * 128, n0 = by * 128;
    const int tid = threadIdx.x;
    const int tc = tid & 15, tr = tid >> 4;

    const int ack = tid >> 4, acp = (tid & 15) * 8;   // A stage: 16ck x 128c'
    const int bn  = tid >> 1, bck = (tid & 1) * 8;    // B stage: 128n x 16ck (transpose)

    float acc[8][8] = {};

    for (int k0 = 0; k0 < C_; k0 += 16) {
        __syncthreads();
        float4 w0 = *(const float4*)(wo + (size_t)(k0 + ack) * C_ + c0 + acp);
        float4 w1 = *(const float4*)(wo + (size_t)(k0 + ack) * C_ + c0 + acp + 4);
        float4 r0 = *(const float4*)(RES + ((size_t)b * N_ + n0 + bn) * C_ + k0 + bck);
        float4 r1 = *(const float4*)(RES + ((size_t)b * N_ + n0 + bn) * C_ + k0 + bck + 4);
        *(float4*)&As[ack][acp]     = w0;
        *(float4*)&As[ack][acp + 4] = w1;
        Bs[bck + 0][bn] = r0.x;
        Bs[bck + 1][bn] = r0.y;
        Bs[bck + 2][bn] = r0.z;
        Bs[bck + 3][bn] = r0.w;
        Bs[bck + 4][bn] = r1.x;
        Bs[bck + 5][bn] = r1.y;
        Bs[bck + 6][bn] = r1.z;
        Bs[bck + 7][bn] = r1.w;
        __syncthreads();

#pragma unroll
        for (int kk = 0; kk < 16; ++kk) {
            float4 a0 = *(const float4*)&As[kk][tr * 8];
            float4 a1 = *(const float4*)&As[kk][tr * 8 + 4];
            float4 b0 = *(const float4*)&Bs[kk][tc * 8];
            float4 b1 = *(const float4*)&Bs[kk][tc * 8 + 4];
            float av[8] = {a0.x, a0.y, a0.z, a0.w, a1.x, a1.y, a1.z, a1.w};
            float bv[8] = {b0.x, b0.y, b0.z, b0.w, b1.x, b1.y, b1.z, b1.w};
#pragma unroll
            for (int i = 0; i < 8; ++i)
#pragma unroll
                for (int j = 0; j < 8; ++j)
                    acc[i][j] += av[i] * bv[j];
        }
    }

    // epilogue: bias + residual + coalesced store (rows are output channels)
    const size_t obase = ((size_t)b * C_ + c0 + tr * 8) * N_ + n0 + tc * 8;
#pragma unroll
    for (int i = 0; i < 8; ++i) {
        float bias = bo[c0 + tr * 8 + i];
        float4 x0 = *(const float4*)(x + obase + (size_t)i * N_);
        float4 x1 = *(const float4*)(x + obase + (size_t)i * N_ + 4);
        float4 o0 = make_float4(acc[i][0] + bias + x0.x, acc[i][1] + bias + x0.y,
                                acc[i][2] + bias + x0.z, acc[i][3] + bias + x0.w);
        float4 o1 = make_float4(acc[i][4] + bias + x1.x, acc[i][5] + bias + x1.y,
                                acc[i][6] + bias + x1.z, acc[i][7] + bias + x1.w);
        *(float4*)(out + obase + (size_t)i * N_)     = o0;
        *(float4*)(out + obase + (size_t)i * N_ + 4) = o1;
    }
}

extern "C" void kernel_launch(void* const* d_in, const int* in_sizes, int n_in,
                              void* d_out, int out_size, void* d_ws, size_t ws_size,
                              hipStream_t stream) {
    const float* x  = (const float*)d_in[0];
    const float* wp = (const float*)d_in[1];
    const float* bp = (const float*)d_in[2];
    const float* wo = (const float*)d_in[3];
    const float* bo = (const float*)d_in[4];
    float* out = (float*)d_out;

    // workspace: Q,K,V [B][NH][N][DK] + RES [B][N][C]  = 4 x 32MiB = 128MiB
    const size_t seg = (size_t)B_ * NH * N_ * DK;   // 8388608 floats
    float* Q   = (float*)d_ws;
    float* K   = Q + seg;
    float* V   = K + seg;
    float* RES = V + seg;

    qkv_proj_kernel<<<dim3(12, 8, 16), 256, 0, stream>>>(x, wp, bp, Q, K, V);
    attn_kernel<<<dim3(16, 64), 256, 0, stream>>>(Q, K, V, RES);
    out_proj_kernel<<<dim3(4, 8, 16), 256, 0, stream>>>(RES, wo, bo, x, out);
}

// Round 3
// 738.006 us; speedup vs baseline: 1.3489x; 1.3489x over previous
//
#include <hip/hip_runtime.h>

#define B_  16
#define C_  512
#define N_  1024
#define NH  4
#define DK  128
#define M3  1536   // 3*C

typedef unsigned short u16;
typedef unsigned int   u32;
typedef __attribute__((ext_vector_type(8))) short bfrag;   // 8 bf16 (4 VGPR)
typedef __attribute__((ext_vector_type(4))) float f4;      // MFMA C/D

#define MFMA(a, b, c) __builtin_amdgcn_mfma_f32_16x16x32_bf16(a, b, c, 0, 0, 0)

// async global->LDS, 16B per lane, lane l lands at lds_base + l*16
#define GL2LDS(gp, lp) __builtin_amdgcn_global_load_lds( \
    (__attribute__((address_space(1))) const unsigned int*)(const void*)(gp), \
    (__attribute__((address_space(3))) unsigned int*)(void*)(lp), 16, 0, 0)

__device__ __forceinline__ u16 f2bf(float f) {            // RNE fp32->bf16 (no NaN inputs)
    u32 u = __float_as_uint(f);
    return (u16)((u + 0x7FFFu + ((u >> 16) & 1u)) >> 16);
}
__device__ __forceinline__ float bf2f(u16 h) { return __uint_as_float(((u32)h) << 16); }

// ---------------------------------------------------------------------------
// Convert: src fp32 [R][Cc] (batched via z) -> dst_hi/lo bf16 [Cc][R] (transpose+split)
// 64x64 tile, 256 threads, LDS bounce.
// ---------------------------------------------------------------------------
__global__ __launch_bounds__(256) void conv_split_t(
    const float* __restrict__ src, u16* __restrict__ dhi, u16* __restrict__ dlo,
    int R, int Cc)
{
    __shared__ float Ts[64][65];
    const int tid = threadIdx.x;
    const int c0 = blockIdx.x * 64, r0 = blockIdx.y * 64;
    const size_t bofs = (size_t)blockIdx.z * R * Cc;   // same stride for src and dst

#pragma unroll
    for (int p = 0; p < 4; ++p) {
        int r = p * 16 + (tid >> 4);
        int c = (tid & 15) * 4;
        float4 v = *(const float4*)(src + bofs + (size_t)(r0 + r) * Cc + c0 + c);
        Ts[c + 0][r] = v.x; Ts[c + 1][r] = v.y; Ts[c + 2][r] = v.z; Ts[c + 3][r] = v.w;
    }
    __syncthreads();
#pragma unroll
    for (int p = 0; p < 4; ++p) {
        int cc = p * 16 + (tid >> 4);
        int rr = (tid & 15) * 4;
        float f0 = Ts[cc][rr + 0], f1 = Ts[cc][rr + 1];
        float f2 = Ts[cc][rr + 2], f3 = Ts[cc][rr + 3];
        u16 h0 = f2bf(f0), h1 = f2bf(f1), h2 = f2bf(f2), h3 = f2bf(f3);
        u16 l0 = f2bf(f0 - bf2f(h0)), l1 = f2bf(f1 - bf2f(h1));
        u16 l2 = f2bf(f2 - bf2f(h2)), l3 = f2bf(f3 - bf2f(h3));
        size_t o = bofs + (size_t)(c0 + cc) * R + r0 + rr;
        *(uint2*)(void*)(dhi + o) = make_uint2((u32)h0 | ((u32)h1 << 16), (u32)h2 | ((u32)h3 << 16));
        *(uint2*)(void*)(dlo + o) = make_uint2((u32)l0 | ((u32)l1 << 16), (u32)l2 | ((u32)l3 << 16));
    }
}

// ---------------------------------------------------------------------------
// QKV projection, split-bf16 MFMA (3 products: hh + hl + lh).
// A = xt [n][c] row-major hi/lo; B^T = wpT [m][c] row-major hi/lo.
// Tile 128x128, BK=64, 4 waves (2x2), per-wave 64x64 = 4x4 frags 16x16x32.
// LDS: 4 x 16KiB, XOR-16B-chunk swizzle (pre-swizzled global source).
// ---------------------------------------------------------------------------
__global__ __launch_bounds__(256, 2) void qkv_mfma(
    const u16* __restrict__ xt_hi, const u16* __restrict__ xt_lo,
    const u16* __restrict__ wpT_hi, const u16* __restrict__ wpT_lo,
    const float* __restrict__ bp,
    float* __restrict__ Q, float* __restrict__ K, float* __restrict__ V)
{
    __shared__ __align__(16) u16 AH[128 * 64], AL[128 * 64], BH[128 * 64], BL[128 * 64];
    const int tid = threadIdx.x;
    const int l = tid & 63, w = tid >> 6;
    const int wr = w >> 1, wc = w & 1;
    const int lm = l & 15, kg = l >> 4;
    const int bx = blockIdx.x, by = blockIdx.y, b = blockIdx.z;
    const int m0 = bx * 128, n0 = by * 128;

    // wave w stages array w; lane offset encodes row (l>>3) and swizzled 16B chunk
    const u16* gsrc =
        (w == 0) ? xt_hi + ((size_t)b * N_ + n0) * C_ :
        (w == 1) ? xt_lo + ((size_t)b * N_ + n0) * C_ :
        (w == 2) ? wpT_hi + (size_t)m0 * C_ :
                   wpT_lo + (size_t)m0 * C_;
    u16* ldst = (w == 0) ? AH : (w == 1) ? AL : (w == 2) ? BH : BL;
    const int lane_off = (l >> 3) * C_ + (((l & 7) ^ (l >> 3)) << 3);

    f4 acc[4][4] = {};

    for (int it = 0; it < 8; ++it) {
        __syncthreads();                       // prior tile's reads complete
        const u16* g = gsrc + it * 64 + lane_off;
#pragma unroll
        for (int u = 0; u < 16; ++u)
            GL2LDS(g + (size_t)u * 8 * C_, ldst + u * 512);
        __syncthreads();                       // drains vmcnt(0) before barrier

#pragma unroll
        for (int kk = 0; kk < 2; ++kk) {
            bfrag ah[4], al[4], bh[4], bl[4];
            const int s = ((kk * 4 + kg) ^ (lm & 7)) << 3;   // swizzled chunk (ushorts)
#pragma unroll
            for (int f = 0; f < 4; ++f) {
                const int ar = wr * 64 + f * 16 + lm;
                const int br = wc * 64 + f * 16 + lm;
                ah[f] = *(const bfrag*)(AH + ar * 64 + s);
                al[f] = *(const bfrag*)(AL + ar * 64 + s);
                bh[f] = *(const bfrag*)(BH + br * 64 + s);
                bl[f] = *(const bfrag*)(BL + br * 64 + s);
            }
#pragma unroll
            for (int i = 0; i < 4; ++i)
#pragma unroll
                for (int j = 0; j < 4; ++j) {
                    acc[i][j] = MFMA(ah[i], bh[j], acc[i][j]);
                    acc[i][j] = MFMA(ah[i], bl[j], acc[i][j]);
                    acc[i][j] = MFMA(al[i], bh[j], acc[i][j]);
                }
        }
    }

    // epilogue: route 128-col tile to Q/K/V, add bias, fp32 stores
    const int hh = bx / 3, t = bx - hh * 3;
    float* dst = (t == 0) ? Q : (t == 1) ? K : V;
#pragma unroll
    for (int j = 0; j < 4; ++j) {
        const int mcol = m0 + wc * 64 + j * 16 + lm;
        const float bias = bp[mcol];
        const int d = mcol & 127;
#pragma unroll
        for (int i = 0; i < 4; ++i) {
            const int tok = n0 + wr * 64 + i * 16 + kg * 4;
            float* p = dst + ((size_t)(b * NH + hh) * N_ + tok) * DK + d;
#pragma unroll
            for (int r = 0; r < 4; ++r)
                p[(size_t)r * DK] = acc[i][j][r] + bias;
        }
    }
}

// ---------------------------------------------------------------------------
// Flash attention (fp32 VALU) — math identical to verified round-2 kernel;
// only the epilogue changed: writes res as bf16 hi/lo (split for out-proj MFMA).
// ---------------------------------------------------------------------------
__global__ __launch_bounds__(256) void attn_kernel(
    const float* __restrict__ Q, const float* __restrict__ K,
    const float* __restrict__ V, u16* __restrict__ res_hi, u16* __restrict__ res_lo)
{
    __shared__ float Qt[128][68];
    __shared__ float Kt[64][68];
    __shared__ float Ps[64][68];

    const int bh = blockIdx.y;
    const int i0 = blockIdx.x * 64;
    const int b  = bh >> 2, h = bh & 3;
    const int tid = threadIdx.x;
    const int tc = tid & 15, tr = tid >> 4;
    const float scale = 0.08838834764831845f;

    const float* Qg = Q + ((size_t)bh * N_ + i0) * DK;
    const float* Kg = K + (size_t)bh * N_ * DK;
    const float* Vg = V + (size_t)bh * N_ * DK;

    {
        const int i = tid >> 2, d0 = (tid & 3) * 32;
        const float* qp = Qg + (size_t)i * DK + d0;
#pragma unroll
        for (int u = 0; u < 32; u += 4) {
            float4 v4 = *(const float4*)(qp + u);
            Qt[d0 + u + 0][i] = v4.x * scale;
            Qt[d0 + u + 1][i] = v4.y * scale;
            Qt[d0 + u + 2][i] = v4.z * scale;
            Qt[d0 + u + 3][i] = v4.w * scale;
        }
    }

    float m_i[4], l_i[4], o_acc[4][8];
#pragma unroll
    for (int ii = 0; ii < 4; ++ii) {
        m_i[ii] = -1e30f;
        l_i[ii] = 0.f;
#pragma unroll
        for (int dd = 0; dd < 8; ++dd) o_acc[ii][dd] = 0.f;
    }

    for (int j0 = 0; j0 < N_; j0 += 64) {
        float s[4][4] = {};

#pragma unroll
        for (int dc = 0; dc < 128; dc += 64) {
            __syncthreads();
            {
                const int j = tid >> 2, dd0 = (tid & 3) * 16;
                const float* kp = Kg + (size_t)(j0 + j) * DK + dc + dd0;
#pragma unroll
                for (int u = 0; u < 16; u += 4) {
                    float4 v4 = *(const float4*)(kp + u);
                    Kt[dd0 + u + 0][j] = v4.x;
                    Kt[dd0 + u + 1][j] = v4.y;
                    Kt[dd0 + u + 2][j] = v4.z;
                    Kt[dd0 + u + 3][j] = v4.w;
                }
            }
            __syncthreads();

#pragma unroll 16
            for (int kk = 0; kk < 64; ++kk) {
                float4 a4 = *(const float4*)&Qt[dc + kk][tr * 4];
                float4 b4 = *(const float4*)&Kt[kk][tc * 4];
                float av[4] = {a4.x, a4.y, a4.z, a4.w};
                float bv[4] = {b4.x, b4.y, b4.z, b4.w};
#pragma unroll
                for (int ii = 0; ii < 4; ++ii)
#pragma unroll
                    for (int jj = 0; jj < 4; ++jj)
                        s[ii][jj] += av[ii] * bv[jj];
            }
        }

#pragma unroll
        for (int ii = 0; ii < 4; ++ii) {
            float rm = fmaxf(fmaxf(s[ii][0], s[ii][1]), fmaxf(s[ii][2], s[ii][3]));
            rm = fmaxf(rm, __shfl_xor(rm, 1));
            rm = fmaxf(rm, __shfl_xor(rm, 2));
            rm = fmaxf(rm, __shfl_xor(rm, 4));
            rm = fmaxf(rm, __shfl_xor(rm, 8));
            float mn = fmaxf(m_i[ii], rm);
            float al = __expf(m_i[ii] - mn);
            m_i[ii] = mn;
            float rs = 0.f;
#pragma unroll
            for (int jj = 0; jj < 4; ++jj) {
                s[ii][jj] = __expf(s[ii][jj] - mn);
                rs += s[ii][jj];
            }
            rs += __shfl_xor(rs, 1);
            rs += __shfl_xor(rs, 2);
            rs += __shfl_xor(rs, 4);
            rs += __shfl_xor(rs, 8);
            l_i[ii] = l_i[ii] * al + rs;
#pragma unroll
            for (int dd = 0; dd < 8; ++dd) o_acc[ii][dd] *= al;
        }

#pragma unroll
        for (int ii = 0; ii < 4; ++ii)
#pragma unroll
            for (int jj = 0; jj < 4; ++jj)
                Ps[tc * 4 + jj][tr * 4 + ii] = s[ii][jj];
        __syncthreads();

        const float* vg = Vg + (size_t)j0 * DK + tc * 8;
#pragma unroll 8
        for (int j = 0; j < 64; ++j) {
            float4 p4 = *(const float4*)&Ps[j][tr * 4];
            float4 v0 = *(const float4*)(vg + (size_t)j * DK);
            float4 v1 = *(const float4*)(vg + (size_t)j * DK + 4);
            float pv[4] = {p4.x, p4.y, p4.z, p4.w};
            float vv[8] = {v0.x, v0.y, v0.z, v0.w, v1.x, v1.y, v1.z, v1.w};
#pragma unroll
            for (int ii = 0; ii < 4; ++ii)
#pragma unroll
                for (int dd = 0; dd < 8; ++dd)
                    o_acc[ii][dd] += pv[ii] * vv[dd];
        }
    }

    // epilogue: res[b][n][h*128+d] as bf16 hi/lo
    const size_t off0 = ((size_t)b * N_ + i0 + tr * 4) * C_ + h * DK + tc * 8;
#pragma unroll
    for (int ii = 0; ii < 4; ++ii) {
        float inv = 1.f / l_i[ii];
        u16 hb[8], lb[8];
#pragma unroll
        for (int dd = 0; dd < 8; ++dd) {
            float v = o_acc[ii][dd] * inv;
            hb[dd] = f2bf(v);
            lb[dd] = f2bf(v - bf2f(hb[dd]));
        }
        size_t off = off0 + (size_t)ii * C_;
        *(uint4*)(void*)(res_hi + off) = make_uint4(
            (u32)hb[0] | ((u32)hb[1] << 16), (u32)hb[2] | ((u32)hb[3] << 16),
            (u32)hb[4] | ((u32)hb[5] << 16), (u32)hb[6] | ((u32)hb[7] << 16));
        *(uint4*)(void*)(res_lo + off) = make_uint4(
            (u32)lb[0] | ((u32)lb[1] << 16), (u32)lb[2] | ((u32)lb[3] << 16),
            (u32)lb[4] | ((u32)lb[5] << 16), (u32)lb[6] | ((u32)lb[7] << 16));
    }
}

// ---------------------------------------------------------------------------
// Out projection, split-bf16 MFMA, computes outT[c'][n] directly.
// A = woT [c'][c] hi/lo; B^T = res [n][c] hi/lo. Epilogue: +bias +x residual.
// ---------------------------------------------------------------------------
__global__ __launch_bounds__(256, 2) void out_mfma(
    const u16* __restrict__ woT_hi, const u16* __restrict__ woT_lo,
    const u16* __restrict__ res_hi, const u16* __restrict__ res_lo,
    const float* __restrict__ bo, const float* __restrict__ x,
    float* __restrict__ out)
{
    __shared__ __align__(16) u16 AH[128 * 64], AL[128 * 64], BH[128 * 64], BL[128 * 64];
    const int tid = threadIdx.x;
    const int l = tid & 63, w = tid >> 6;
    const int wr = w >> 1, wc = w & 1;
    const int lm = l & 15, kg = l >> 4;
    const int bx = blockIdx.x, by = blockIdx.y, b = blockIdx.z;
    const int c0 = bx * 128, n0 = by * 128;

    const u16* gsrc =
        (w == 0) ? woT_hi + (size_t)c0 * C_ :
        (w == 1) ? woT_lo + (size_t)c0 * C_ :
        (w == 2) ? res_hi + ((size_t)b * N_ + n0) * C_ :
                   res_lo + ((size_t)b * N_ + n0) * C_;
    u16* ldst = (w == 0) ? AH : (w == 1) ? AL : (w == 2) ? BH : BL;
    const int lane_off = (l >> 3) * C_ + (((l & 7) ^ (l >> 3)) << 3);

    f4 acc[4][4] = {};

    for (int it = 0; it < 8; ++it) {
        __syncthreads();
        const u16* g = gsrc + it * 64 + lane_off;
#pragma unroll
        for (int u = 0; u < 16; ++u)
            GL2LDS(g + (size_t)u * 8 * C_, ldst + u * 512);
        __syncthreads();

#pragma unroll
        for (int kk = 0; kk < 2; ++kk) {
            bfrag ah[4], al[4], bh[4], bl[4];
            const int s = ((kk * 4 + kg) ^ (lm & 7)) << 3;
#pragma unroll
            for (int f = 0; f < 4; ++f) {
                const int ar = wr * 64 + f * 16 + lm;
                const int br = wc * 64 + f * 16 + lm;
                ah[f] = *(const bfrag*)(AH + ar * 64 + s);
                al[f] = *(const bfrag*)(AL + ar * 64 + s);
                bh[f] = *(const bfrag*)(BH + br * 64 + s);
                bl[f] = *(const bfrag*)(BL + br * 64 + s);
            }
#pragma unroll
            for (int i = 0; i < 4; ++i)
#pragma unroll
                for (int j = 0; j < 4; ++j) {
                    acc[i][j] = MFMA(ah[i], bh[j], acc[i][j]);
                    acc[i][j] = MFMA(ah[i], bl[j], acc[i][j]);
                    acc[i][j] = MFMA(al[i], bh[j], acc[i][j]);
                }
        }
    }

    // epilogue: out[b][c'][n] = acc + bo[c'] + x[b][c'][n]  (coalesced over n)
#pragma unroll
    for (int j = 0; j < 4; ++j) {
        const int ncol = n0 + wc * 64 + j * 16 + lm;
#pragma unroll
        for (int i = 0; i < 4; ++i) {
#pragma unroll
            for (int r = 0; r < 4; ++r) {
                const int crow = c0 + wr * 64 + i * 16 + kg * 4 + r;
                const size_t o = ((size_t)b * C_ + crow) * N_ + ncol;
                out[o] = acc[i][j][r] + bo[crow] + x[o];
            }
        }
    }
}

extern "C" void kernel_launch(void* const* d_in, const int* in_sizes, int n_in,
                              void* d_out, int out_size, void* d_ws, size_t ws_size,
                              hipStream_t stream) {
    const float* x  = (const float*)d_in[0];
    const float* wp = (const float*)d_in[1];
    const float* bp = (const float*)d_in[2];
    const float* wo = (const float*)d_in[3];
    const float* bo = (const float*)d_in[4];
    float* out = (float*)d_out;

    // ws map (exactly 128 MiB, the proven budget):
    //  [0,16M):  xt_hi  -> res_hi after qkv     [16M,32M): xt_lo -> res_lo
    //  [32M,64M): Q fp32 (woT hi/lo reuse after attn)  [64M,96M): K  [96M,128M): V
    // d_out[0,3M): wpT hi/lo (dead before out_mfma writes output over it)
    const size_t SEG = (size_t)B_ * N_ * C_;     // 8388608 (== B*NH*N*DK)
    u16* xt_hi = (u16*)d_ws;
    u16* xt_lo = xt_hi + SEG;
    float* Q = (float*)(xt_hi + 2 * SEG);
    float* K = Q + SEG;
    float* V = K + SEG;
    u16* res_hi = xt_hi;
    u16* res_lo = xt_lo;
    u16* woT_hi = (u16*)Q;
    u16* woT_lo = woT_hi + C_ * C_;
    u16* wpT_hi = (u16*)d_out;
    u16* wpT_lo = wpT_hi + C_ * M3;

    // 1) transpose+split x -> xt[b][n][c], wp -> wpT[m][c] (into d_out)
    conv_split_t<<<dim3(16, 8, 16), 256, 0, stream>>>(x, xt_hi, xt_lo, C_, N_);
    conv_split_t<<<dim3(24, 8, 1), 256, 0, stream>>>(wp, wpT_hi, wpT_lo, C_, M3);
    // 2) QKV projection (MFMA)
    qkv_mfma<<<dim3(12, 8, 16), 256, 0, stream>>>(xt_hi, xt_lo, wpT_hi, wpT_lo, bp, Q, K, V);
    // 3) attention (fp32 VALU, unchanged math) -> res hi/lo over dead xt
    attn_kernel<<<dim3(16, 64), 256, 0, stream>>>(Q, K, V, res_hi, res_lo);
    // 4) wo -> woT[c'][c] into dead Q region
    conv_split_t<<<dim3(8, 8, 1), 256, 0, stream>>>(wo, woT_hi, woT_lo, C_, C_);
    // 5) out projection (MFMA) + bias + residual
    out_mfma<<<dim3(4, 8, 16), 256, 0, stream>>>(woT_hi, woT_lo, res_hi, res_lo, bo, x, out);
}

// Round 4
// 720.898 us; speedup vs baseline: 1.3809x; 1.0237x over previous
//
#include <hip/hip_runtime.h>

#define B_  16
#define C_  512
#define N_  1024
#define NH  4
#define DK  128
#define M3  1536   // 3*C

typedef unsigned short u16;
typedef unsigned int   u32;
typedef __attribute__((ext_vector_type(8))) short bfrag;   // 8 bf16 (4 VGPR)
typedef __attribute__((ext_vector_type(4))) float f4;      // MFMA C/D

#define MFMA(a, b, c) __builtin_amdgcn_mfma_f32_16x16x32_bf16(a, b, c, 0, 0, 0)

// async global->LDS, 16B per lane, lane l lands at lds_base + l*16
#define GL2LDS(gp, lp) __builtin_amdgcn_global_load_lds( \
    (__attribute__((address_space(1))) const unsigned int*)(const void*)(gp), \
    (__attribute__((address_space(3))) unsigned int*)(void*)(lp), 16, 0, 0)

__device__ __forceinline__ u16 f2bf(float f) {            // RNE fp32->bf16 (no NaN inputs)
    u32 u = __float_as_uint(f);
    return (u16)((u + 0x7FFFu + ((u >> 16) & 1u)) >> 16);
}
__device__ __forceinline__ float bf2f(u16 h) { return __uint_as_float(((u32)h) << 16); }

// dk^-0.5 * log2(e): folded into stored Q so attn uses exp2 directly
#define QSCL 0.12751741859316937f

// ---------------------------------------------------------------------------
// Convert: src fp32 [R][Cc] (batched via z) -> dst_hi/lo bf16 [Cc][R] (transpose+split)
// ---------------------------------------------------------------------------
__global__ __launch_bounds__(256) void conv_split_t(
    const float* __restrict__ src, u16* __restrict__ dhi, u16* __restrict__ dlo,
    int R, int Cc)
{
    __shared__ float Ts[64][65];
    const int tid = threadIdx.x;
    const int c0 = blockIdx.x * 64, r0 = blockIdx.y * 64;
    const size_t bofs = (size_t)blockIdx.z * R * Cc;

#pragma unroll
    for (int p = 0; p < 4; ++p) {
        int r = p * 16 + (tid >> 4);
        int c = (tid & 15) * 4;
        float4 v = *(const float4*)(src + bofs + (size_t)(r0 + r) * Cc + c0 + c);
        Ts[c + 0][r] = v.x; Ts[c + 1][r] = v.y; Ts[c + 2][r] = v.z; Ts[c + 3][r] = v.w;
    }
    __syncthreads();
#pragma unroll
    for (int p = 0; p < 4; ++p) {
        int cc = p * 16 + (tid >> 4);
        int rr = (tid & 15) * 4;
        float f0 = Ts[cc][rr + 0], f1 = Ts[cc][rr + 1];
        float f2 = Ts[cc][rr + 2], f3 = Ts[cc][rr + 3];
        u16 h0 = f2bf(f0), h1 = f2bf(f1), h2 = f2bf(f2), h3 = f2bf(f3);
        u16 l0 = f2bf(f0 - bf2f(h0)), l1 = f2bf(f1 - bf2f(h1));
        u16 l2 = f2bf(f2 - bf2f(h2)), l3 = f2bf(f3 - bf2f(h3));
        size_t o = bofs + (size_t)(c0 + cc) * R + r0 + rr;
        *(uint2*)(void*)(dhi + o) = make_uint2((u32)h0 | ((u32)h1 << 16), (u32)h2 | ((u32)h3 << 16));
        *(uint2*)(void*)(dlo + o) = make_uint2((u32)l0 | ((u32)l1 << 16), (u32)l2 | ((u32)l3 << 16));
    }
}

// ---------------------------------------------------------------------------
// QKV projection, split-bf16 MFMA. Epilogue writes attention-ready operands:
//   Q hi/lo [b][h][n][d]  (prescaled by dk^-0.5*log2e)
//   K hi/lo [b][h][n][d]
//   Vt hi/lo [b][h][d][n] (transposed for PV A-operand)
// ---------------------------------------------------------------------------
__global__ __launch_bounds__(256, 2) void qkv_mfma(
    const u16* __restrict__ xt_hi, const u16* __restrict__ xt_lo,
    const u16* __restrict__ wpT_hi, const u16* __restrict__ wpT_lo,
    const float* __restrict__ bp,
    u16* __restrict__ Qh, u16* __restrict__ Ql,
    u16* __restrict__ Kh, u16* __restrict__ Kl,
    u16* __restrict__ Vth, u16* __restrict__ Vtl)
{
    __shared__ __align__(16) u16 AH[128 * 64], AL[128 * 64], BH[128 * 64], BL[128 * 64];
    const int tid = threadIdx.x;
    const int l = tid & 63, w = tid >> 6;
    const int wr = w >> 1, wc = w & 1;
    const int lm = l & 15, kg = l >> 4;
    const int bx = blockIdx.x, by = blockIdx.y, b = blockIdx.z;
    const int m0 = bx * 128, n0 = by * 128;

    const u16* gsrc =
        (w == 0) ? xt_hi + ((size_t)b * N_ + n0) * C_ :
        (w == 1) ? xt_lo + ((size_t)b * N_ + n0) * C_ :
        (w == 2) ? wpT_hi + (size_t)m0 * C_ :
                   wpT_lo + (size_t)m0 * C_;
    u16* ldst = (w == 0) ? AH : (w == 1) ? AL : (w == 2) ? BH : BL;
    const int lane_off = (l >> 3) * C_ + (((l & 7) ^ (l >> 3)) << 3);

    f4 acc[4][4] = {};

    for (int it = 0; it < 8; ++it) {
        __syncthreads();
        const u16* g = gsrc + it * 64 + lane_off;
#pragma unroll
        for (int u = 0; u < 16; ++u)
            GL2LDS(g + (size_t)u * 8 * C_, ldst + u * 512);
        __syncthreads();

#pragma unroll
        for (int kk = 0; kk < 2; ++kk) {
            bfrag ah[4], al[4], bh[4], bl[4];
            const int s = ((kk * 4 + kg) ^ (lm & 7)) << 3;
#pragma unroll
            for (int f = 0; f < 4; ++f) {
                const int ar = wr * 64 + f * 16 + lm;
                const int br = wc * 64 + f * 16 + lm;
                ah[f] = *(const bfrag*)(AH + ar * 64 + s);
                al[f] = *(const bfrag*)(AL + ar * 64 + s);
                bh[f] = *(const bfrag*)(BH + br * 64 + s);
                bl[f] = *(const bfrag*)(BL + br * 64 + s);
            }
#pragma unroll
            for (int i = 0; i < 4; ++i)
#pragma unroll
                for (int j = 0; j < 4; ++j) {
                    acc[i][j] = MFMA(ah[i], bh[j], acc[i][j]);
                    acc[i][j] = MFMA(ah[i], bl[j], acc[i][j]);
                    acc[i][j] = MFMA(al[i], bh[j], acc[i][j]);
                }
        }
    }

    // epilogue: split-bf16 stores into attention layouts
    const int hh = bx / 3, t = bx - hh * 3;
#pragma unroll
    for (int j = 0; j < 4; ++j) {
        const int mcol = m0 + wc * 64 + j * 16 + lm;
        const float bias = bp[mcol];
        const int d = mcol & 127;
#pragma unroll
        for (int i = 0; i < 4; ++i) {
            const int tok = n0 + wr * 64 + i * 16 + kg * 4;
            if (t == 2) {
                // V: transposed, pack 4 consecutive tokens into uint2
                u16 hb[4], lb[4];
#pragma unroll
                for (int r = 0; r < 4; ++r) {
                    float v = acc[i][j][r] + bias;
                    hb[r] = f2bf(v);
                    lb[r] = f2bf(v - bf2f(hb[r]));
                }
                const size_t o = ((size_t)(b * NH + hh) * DK + d) * N_ + tok;
                *(uint2*)(void*)(Vth + o) = make_uint2((u32)hb[0] | ((u32)hb[1] << 16),
                                                       (u32)hb[2] | ((u32)hb[3] << 16));
                *(uint2*)(void*)(Vtl + o) = make_uint2((u32)lb[0] | ((u32)lb[1] << 16),
                                                       (u32)lb[2] | ((u32)lb[3] << 16));
            } else {
                u16* dh = (t == 0) ? Qh : Kh;
                u16* dl = (t == 0) ? Ql : Kl;
                const size_t o = ((size_t)(b * NH + hh) * N_ + tok) * DK + d;
#pragma unroll
                for (int r = 0; r < 4; ++r) {
                    float v = acc[i][j][r] + bias;
                    if (t == 0) v *= QSCL;
                    u16 hb = f2bf(v);
                    dh[o + (size_t)r * DK] = hb;
                    dl[o + (size_t)r * DK] = f2bf(v - bf2f(hb));
                }
            }
        }
    }
}

// ---------------------------------------------------------------------------
// Flash attention, split-bf16 MFMA, swapped operands (S^T = K·Q^T).
// 512 threads = 8 waves; wave owns 16 q-rows; lane owns ONE q-row (col=lm).
// K/V read direct from global (L2-resident per head); P bounced through
// per-wave-private LDS (no __syncthreads in the whole kernel).
// ---------------------------------------------------------------------------
__global__ __launch_bounds__(512) void attn_mfma(
    const u16* __restrict__ Qh_, const u16* __restrict__ Ql_,
    const u16* __restrict__ Kh_, const u16* __restrict__ Kl_,
    const u16* __restrict__ Vth_, const u16* __restrict__ Vtl_,
    u16* __restrict__ res_hi, u16* __restrict__ res_lo)
{
    __shared__ u16 Ph[8][16][72], Pl[8][16][72];   // per-wave private P tiles

    const int tid = threadIdx.x;
    const int l = tid & 63, w = tid >> 6;
    const int lm = l & 15, kg = l >> 4;
    const int bh = blockIdx.x;            // 0..63 (b*NH+h)
    const int qc = blockIdx.y;            // 0..7
    const int i = qc * 128 + w * 16 + lm; // this lane's q-row
    const size_t head = (size_t)bh * N_ * DK;

    // Q fragments (B-operand): lane holds Q[i][kc*32 + kg*8 .. +7], hi/lo
    bfrag qfh[4], qfl[4];
    {
        const u16* qp = Qh_ + head + (size_t)i * DK + kg * 8;
        const u16* qp2 = Ql_ + head + (size_t)i * DK + kg * 8;
#pragma unroll
        for (int kc = 0; kc < 4; ++kc) {
            qfh[kc] = *(const bfrag*)(qp + kc * 32);
            qfl[kc] = *(const bfrag*)(qp2 + kc * 32);
        }
    }

    f4 acc_o[8] = {};
    float m_r = -3.0e38f, l_r = 0.f;

    for (int jt = 0; jt < 16; ++jt) {
        // ---- S^T = K·Q^T over d=128 (split: KhQh + KhQl + KlQh) ----
        f4 sacc[4] = {};
#pragma unroll
        for (int kc = 0; kc < 4; ++kc) {
#pragma unroll
            for (int jf = 0; jf < 4; ++jf) {
                const size_t ko = head + (size_t)(jt * 64 + jf * 16 + lm) * DK + kc * 32 + kg * 8;
                bfrag kh = *(const bfrag*)(Kh_ + ko);
                bfrag kl = *(const bfrag*)(Kl_ + ko);
                sacc[jf] = MFMA(kh, qfh[kc], sacc[jf]);
                sacc[jf] = MFMA(kh, qfl[kc], sacc[jf]);
                sacc[jf] = MFMA(kl, qfh[kc], sacc[jf]);
            }
        }

        // ---- online softmax: lane holds 16 logits of its own q-row ----
        float mt = sacc[0][0];
#pragma unroll
        for (int jf = 0; jf < 4; ++jf)
#pragma unroll
            for (int r = 0; r < 4; ++r) mt = fmaxf(mt, sacc[jf][r]);
        mt = fmaxf(mt, __shfl_xor(mt, 16));
        mt = fmaxf(mt, __shfl_xor(mt, 32));
        const float mn = fmaxf(m_r, mt);
        const float alpha = exp2f(m_r - mn);
        m_r = mn;

        float p[16];
        float rs = 0.f;
#pragma unroll
        for (int jf = 0; jf < 4; ++jf)
#pragma unroll
            for (int r = 0; r < 4; ++r) {
                float pv = exp2f(sacc[jf][r] - mn);
                p[jf * 4 + r] = pv;
                rs += pv;
            }
        rs += __shfl_xor(rs, 16);
        rs += __shfl_xor(rs, 32);
        l_r = l_r * alpha + rs;
#pragma unroll
        for (int df = 0; df < 8; ++df)
#pragma unroll
            for (int r = 0; r < 4; ++r) acc_o[df][r] *= alpha;

        // ---- P -> per-wave LDS (hi/lo), B-frag-readable layout ----
#pragma unroll
        for (int jf = 0; jf < 4; ++jf) {
            u16 hb[4], lb[4];
#pragma unroll
            for (int r = 0; r < 4; ++r) {
                float pv = p[jf * 4 + r];
                hb[r] = f2bf(pv);
                lb[r] = f2bf(pv - bf2f(hb[r]));
            }
            *(uint2*)(void*)&Ph[w][lm][jf * 16 + kg * 4] =
                make_uint2((u32)hb[0] | ((u32)hb[1] << 16), (u32)hb[2] | ((u32)hb[3] << 16));
            *(uint2*)(void*)&Pl[w][lm][jf * 16 + kg * 4] =
                make_uint2((u32)lb[0] | ((u32)lb[1] << 16), (u32)lb[2] | ((u32)lb[3] << 16));
        }

        // ---- O^T += Vt · P  (split: VhPh + VhPl + VlPh) ----
#pragma unroll
        for (int kc2 = 0; kc2 < 2; ++kc2) {
            bfrag pbh = *(const bfrag*)&Ph[w][lm][kc2 * 32 + kg * 8];
            bfrag pbl = *(const bfrag*)&Pl[w][lm][kc2 * 32 + kg * 8];
#pragma unroll
            for (int df = 0; df < 8; ++df) {
                const size_t vo = (size_t)bh * DK * N_ + (size_t)(df * 16 + lm) * N_
                                + jt * 64 + kc2 * 32 + kg * 8;
                bfrag vh = *(const bfrag*)(Vth_ + vo);
                bfrag vl = *(const bfrag*)(Vtl_ + vo);
                acc_o[df] = MFMA(vh, pbh, acc_o[df]);
                acc_o[df] = MFMA(vh, pbl, acc_o[df]);
                acc_o[df] = MFMA(vl, pbh, acc_o[df]);
            }
        }
    }

    // ---- epilogue: res[b][i][h*128+d] = O/l as bf16 hi/lo ----
    const float inv = 1.f / l_r;
    const int b = bh >> 2, h = bh & 3;
    const size_t ro = ((size_t)b * N_ + i) * C_ + h * DK;
#pragma unroll
    for (int df = 0; df < 8; ++df) {
        u16 hb[4], lb[4];
#pragma unroll
        for (int r = 0; r < 4; ++r) {
            float v = acc_o[df][r] * inv;
            hb[r] = f2bf(v);
            lb[r] = f2bf(v - bf2f(hb[r]));
        }
        const size_t o = ro + df * 16 + kg * 4;
        *(uint2*)(void*)(res_hi + o) = make_uint2((u32)hb[0] | ((u32)hb[1] << 16),
                                                  (u32)hb[2] | ((u32)hb[3] << 16));
        *(uint2*)(void*)(res_lo + o) = make_uint2((u32)lb[0] | ((u32)lb[1] << 16),
                                                  (u32)lb[2] | ((u32)lb[3] << 16));
    }
}

// ---------------------------------------------------------------------------
// Out projection, split-bf16 MFMA, computes outT[c'][n] directly. (+bias +x)
// ---------------------------------------------------------------------------
__global__ __launch_bounds__(256, 2) void out_mfma(
    const u16* __restrict__ woT_hi, const u16* __restrict__ woT_lo,
    const u16* __restrict__ res_hi, const u16* __restrict__ res_lo,
    const float* __restrict__ bo, const float* __restrict__ x,
    float* __restrict__ out)
{
    __shared__ __align__(16) u16 AH[128 * 64], AL[128 * 64], BH[128 * 64], BL[128 * 64];
    const int tid = threadIdx.x;
    const int l = tid & 63, w = tid >> 6;
    const int wr = w >> 1, wc = w & 1;
    const int lm = l & 15, kg = l >> 4;
    const int bx = blockIdx.x, by = blockIdx.y, b = blockIdx.z;
    const int c0 = bx * 128, n0 = by * 128;

    const u16* gsrc =
        (w == 0) ? woT_hi + (size_t)c0 * C_ :
        (w == 1) ? woT_lo + (size_t)c0 * C_ :
        (w == 2) ? res_hi + ((size_t)b * N_ + n0) * C_ :
                   res_lo + ((size_t)b * N_ + n0) * C_;
    u16* ldst = (w == 0) ? AH : (w == 1) ? AL : (w == 2) ? BH : BL;
    const int lane_off = (l >> 3) * C_ + (((l & 7) ^ (l >> 3)) << 3);

    f4 acc[4][4] = {};

    for (int it = 0; it < 8; ++it) {
        __syncthreads();
        const u16* g = gsrc + it * 64 + lane_off;
#pragma unroll
        for (int u = 0; u < 16; ++u)
            GL2LDS(g + (size_t)u * 8 * C_, ldst + u * 512);
        __syncthreads();

#pragma unroll
        for (int kk = 0; kk < 2; ++kk) {
            bfrag ah[4], al[4], bh[4], bl[4];
            const int s = ((kk * 4 + kg) ^ (lm & 7)) << 3;
#pragma unroll
            for (int f = 0; f < 4; ++f) {
                const int ar = wr * 64 + f * 16 + lm;
                const int br = wc * 64 + f * 16 + lm;
                ah[f] = *(const bfrag*)(AH + ar * 64 + s);
                al[f] = *(const bfrag*)(AL + ar * 64 + s);
                bh[f] = *(const bfrag*)(BH + br * 64 + s);
                bl[f] = *(const bfrag*)(BL + br * 64 + s);
            }
#pragma unroll
            for (int i = 0; i < 4; ++i)
#pragma unroll
                for (int j = 0; j < 4; ++j) {
                    acc[i][j] = MFMA(ah[i], bh[j], acc[i][j]);
                    acc[i][j] = MFMA(ah[i], bl[j], acc[i][j]);
                    acc[i][j] = MFMA(al[i], bh[j], acc[i][j]);
                }
        }
    }

#pragma unroll
    for (int j = 0; j < 4; ++j) {
        const int ncol = n0 + wc * 64 + j * 16 + lm;
#pragma unroll
        for (int i = 0; i < 4; ++i) {
#pragma unroll
            for (int r = 0; r < 4; ++r) {
                const int crow = c0 + wr * 64 + i * 16 + kg * 4 + r;
                const size_t o = ((size_t)b * C_ + crow) * N_ + ncol;
                out[o] = acc[i][j][r] + bo[crow] + x[o];
            }
        }
    }
}

extern "C" void kernel_launch(void* const* d_in, const int* in_sizes, int n_in,
                              void* d_out, int out_size, void* d_ws, size_t ws_size,
                              hipStream_t stream) {
    const float* x  = (const float*)d_in[0];
    const float* wp = (const float*)d_in[1];
    const float* bp = (const float*)d_in[2];
    const float* wo = (const float*)d_in[3];
    const float* bo = (const float*)d_in[4];
    float* out = (float*)d_out;

    // ws map (128 MiB, the proven budget). SEG = 8388608 elements.
    //  [0,32M):   xt hi/lo  -> res hi/lo after qkv
    //  [32M,64M): Q hi/lo   (-> woT hi/lo after attn)
    //  [64M,96M): K hi/lo
    //  [96M,128M): Vt hi/lo
    // d_out[0,3M): wpT hi/lo (dead before out_mfma overwrites with output)
    const size_t SEG = (size_t)B_ * N_ * C_;
    u16* xt_hi = (u16*)d_ws;
    u16* xt_lo = xt_hi + SEG;
    u16* Qh  = xt_hi + 2 * SEG;
    u16* Ql  = Qh + SEG;
    u16* Kh  = Ql + SEG;
    u16* Kl  = Kh + SEG;
    u16* Vth = Kl + SEG;
    u16* Vtl = Vth + SEG;
    u16* res_hi = xt_hi;
    u16* res_lo = xt_lo;
    u16* woT_hi = Qh;
    u16* woT_lo = woT_hi + C_ * C_;
    u16* wpT_hi = (u16*)d_out;
    u16* wpT_lo = wpT_hi + C_ * M3;

    conv_split_t<<<dim3(16, 8, 16), 256, 0, stream>>>(x, xt_hi, xt_lo, C_, N_);
    conv_split_t<<<dim3(24, 8, 1), 256, 0, stream>>>(wp, wpT_hi, wpT_lo, C_, M3);
    qkv_mfma<<<dim3(12, 8, 16), 256, 0, stream>>>(xt_hi, xt_lo, wpT_hi, wpT_lo, bp,
                                                  Qh, Ql, Kh, Kl, Vth, Vtl);
    attn_mfma<<<dim3(64, 8), 512, 0, stream>>>(Qh, Ql, Kh, Kl, Vth, Vtl, res_hi, res_lo);
    conv_split_t<<<dim3(8, 8, 1), 256, 0, stream>>>(wo, woT_hi, woT_lo, C_, C_);
    out_mfma<<<dim3(4, 8, 16), 256, 0, stream>>>(woT_hi, woT_lo, res_hi, res_lo, bo, x, out);
}

// Round 5
// 359.007 us; speedup vs baseline: 2.7728x; 2.0080x over previous
//
#include <hip/hip_runtime.h>

#define B_  16
#define C_  512
#define N_  1024
#define NH  4
#define DK  128
#define M3  1536   // 3*C

typedef unsigned short u16;
typedef unsigned int   u32;
typedef __attribute__((ext_vector_type(8))) short bfrag;   // 8 bf16 (4 VGPR)
typedef __attribute__((ext_vector_type(4))) float f4;      // MFMA C/D

#define MFMA(a, b, c) __builtin_amdgcn_mfma_f32_16x16x32_bf16(a, b, c, 0, 0, 0)

// async global->LDS, 16B per lane, lane l lands at lds_base + l*16
#define GL2LDS(gp, lp) __builtin_amdgcn_global_load_lds( \
    (__attribute__((address_space(1))) const unsigned int*)(const void*)(gp), \
    (__attribute__((address_space(3))) unsigned int*)(void*)(lp), 16, 0, 0)

__device__ __forceinline__ u16 f2bf(float f) {            // RNE fp32->bf16 (no NaN inputs)
    u32 u = __float_as_uint(f);
    return (u16)((u + 0x7FFFu + ((u >> 16) & 1u)) >> 16);
}
__device__ __forceinline__ float bf2f(u16 h) { return __uint_as_float(((u32)h) << 16); }

// dk^-0.5 * log2(e): folded into stored Q so attn uses exp2 directly
#define QSCL 0.12751741859316937f

// ---------------------------------------------------------------------------
// Convert: src fp32 [R][Cc] (batched via z) -> dst_hi/lo bf16 [Cc][R] (transpose+split)
// ---------------------------------------------------------------------------
__global__ __launch_bounds__(256) void conv_split_t(
    const float* __restrict__ src, u16* __restrict__ dhi, u16* __restrict__ dlo,
    int R, int Cc)
{
    __shared__ float Ts[64][65];
    const int tid = threadIdx.x;
    const int c0 = blockIdx.x * 64, r0 = blockIdx.y * 64;
    const size_t bofs = (size_t)blockIdx.z * R * Cc;

#pragma unroll
    for (int p = 0; p < 4; ++p) {
        int r = p * 16 + (tid >> 4);
        int c = (tid & 15) * 4;
        float4 v = *(const float4*)(src + bofs + (size_t)(r0 + r) * Cc + c0 + c);
        Ts[c + 0][r] = v.x; Ts[c + 1][r] = v.y; Ts[c + 2][r] = v.z; Ts[c + 3][r] = v.w;
    }
    __syncthreads();
#pragma unroll
    for (int p = 0; p < 4; ++p) {
        int cc = p * 16 + (tid >> 4);
        int rr = (tid & 15) * 4;
        float f0 = Ts[cc][rr + 0], f1 = Ts[cc][rr + 1];
        float f2 = Ts[cc][rr + 2], f3 = Ts[cc][rr + 3];
        u16 h0 = f2bf(f0), h1 = f2bf(f1), h2 = f2bf(f2), h3 = f2bf(f3);
        u16 l0 = f2bf(f0 - bf2f(h0)), l1 = f2bf(f1 - bf2f(h1));
        u16 l2 = f2bf(f2 - bf2f(h2)), l3 = f2bf(f3 - bf2f(h3));
        size_t o = bofs + (size_t)(c0 + cc) * R + r0 + rr;
        *(uint2*)(void*)(dhi + o) = make_uint2((u32)h0 | ((u32)h1 << 16), (u32)h2 | ((u32)h3 << 16));
        *(uint2*)(void*)(dlo + o) = make_uint2((u32)l0 | ((u32)l1 << 16), (u32)l2 | ((u32)l3 << 16));
    }
}

// ---------------------------------------------------------------------------
// QKV projection, split-bf16 MFMA. Epilogue writes attention-ready operands:
//   Q hi/lo [b][h][n][d] (prescaled by dk^-0.5*log2e), K hi/lo [b][h][n][d],
//   Vt hi/lo [b][h][d][n] (transposed for PV A-operand)
// ---------------------------------------------------------------------------
__global__ __launch_bounds__(256, 2) void qkv_mfma(
    const u16* __restrict__ xt_hi, const u16* __restrict__ xt_lo,
    const u16* __restrict__ wpT_hi, const u16* __restrict__ wpT_lo,
    const float* __restrict__ bp,
    u16* __restrict__ Qh, u16* __restrict__ Ql,
    u16* __restrict__ Kh, u16* __restrict__ Kl,
    u16* __restrict__ Vth, u16* __restrict__ Vtl)
{
    __shared__ __align__(16) u16 AH[128 * 64], AL[128 * 64], BH[128 * 64], BL[128 * 64];
    const int tid = threadIdx.x;
    const int l = tid & 63, w = tid >> 6;
    const int wr = w >> 1, wc = w & 1;
    const int lm = l & 15, kg = l >> 4;
    const int bx = blockIdx.x, by = blockIdx.y, b = blockIdx.z;
    const int m0 = bx * 128, n0 = by * 128;

    const u16* gsrc =
        (w == 0) ? xt_hi + ((size_t)b * N_ + n0) * C_ :
        (w == 1) ? xt_lo + ((size_t)b * N_ + n0) * C_ :
        (w == 2) ? wpT_hi + (size_t)m0 * C_ :
                   wpT_lo + (size_t)m0 * C_;
    u16* ldst = (w == 0) ? AH : (w == 1) ? AL : (w == 2) ? BH : BL;
    const int lane_off = (l >> 3) * C_ + (((l & 7) ^ (l >> 3)) << 3);

    f4 acc[4][4] = {};

    for (int it = 0; it < 8; ++it) {
        __syncthreads();
        const u16* g = gsrc + it * 64 + lane_off;
#pragma unroll
        for (int u = 0; u < 16; ++u)
            GL2LDS(g + (size_t)u * 8 * C_, ldst + u * 512);
        __syncthreads();

#pragma unroll
        for (int kk = 0; kk < 2; ++kk) {
            bfrag ah[4], al[4], bh[4], bl[4];
            const int s = ((kk * 4 + kg) ^ (lm & 7)) << 3;
#pragma unroll
            for (int f = 0; f < 4; ++f) {
                const int ar = wr * 64 + f * 16 + lm;
                const int br = wc * 64 + f * 16 + lm;
                ah[f] = *(const bfrag*)(AH + ar * 64 + s);
                al[f] = *(const bfrag*)(AL + ar * 64 + s);
                bh[f] = *(const bfrag*)(BH + br * 64 + s);
                bl[f] = *(const bfrag*)(BL + br * 64 + s);
            }
#pragma unroll
            for (int i = 0; i < 4; ++i)
#pragma unroll
                for (int j = 0; j < 4; ++j) {
                    acc[i][j] = MFMA(ah[i], bh[j], acc[i][j]);
                    acc[i][j] = MFMA(ah[i], bl[j], acc[i][j]);
                    acc[i][j] = MFMA(al[i], bh[j], acc[i][j]);
                }
        }
    }

    const int hh = bx / 3, t = bx - hh * 3;
#pragma unroll
    for (int j = 0; j < 4; ++j) {
        const int mcol = m0 + wc * 64 + j * 16 + lm;
        const float bias = bp[mcol];
        const int d = mcol & 127;
#pragma unroll
        for (int i = 0; i < 4; ++i) {
            const int tok = n0 + wr * 64 + i * 16 + kg * 4;
            if (t == 2) {
                u16 hb[4], lb[4];
#pragma unroll
                for (int r = 0; r < 4; ++r) {
                    float v = acc[i][j][r] + bias;
                    hb[r] = f2bf(v);
                    lb[r] = f2bf(v - bf2f(hb[r]));
                }
                const size_t o = ((size_t)(b * NH + hh) * DK + d) * N_ + tok;
                *(uint2*)(void*)(Vth + o) = make_uint2((u32)hb[0] | ((u32)hb[1] << 16),
                                                       (u32)hb[2] | ((u32)hb[3] << 16));
                *(uint2*)(void*)(Vtl + o) = make_uint2((u32)lb[0] | ((u32)lb[1] << 16),
                                                       (u32)lb[2] | ((u32)lb[3] << 16));
            } else {
                u16* dh = (t == 0) ? Qh : Kh;
                u16* dl = (t == 0) ? Ql : Kl;
                const size_t o = ((size_t)(b * NH + hh) * N_ + tok) * DK + d;
#pragma unroll
                for (int r = 0; r < 4; ++r) {
                    float v = acc[i][j][r] + bias;
                    if (t == 0) v *= QSCL;
                    u16 hb = f2bf(v);
                    dh[o + (size_t)r * DK] = hb;
                    dl[o + (size_t)r * DK] = f2bf(v - bf2f(hb));
                }
            }
        }
    }
}

// ---------------------------------------------------------------------------
// Flash attention, split-bf16 MFMA, swapped operands (S^T = K·Q^T).
// 512 threads = 8 waves; wave owns 16 q-rows; lane owns ONE q-row.
// K-tile [64][128] and Vt-tile [128][64] hi/lo staged in LDS per jt via
// global_load_lds (pre-swizzled source, chunk ^ (row&7)) and SHARED by all
// 8 waves (fixes round-4's 64x redundant L2 streaming). 2 barriers per jt.
// LDS: 32K (K) + 32K (V) + 36K (P) = 100 KB -> 1 block/CU.
// ---------------------------------------------------------------------------
__global__ __launch_bounds__(512, 2) void attn_mfma(
    const u16* __restrict__ Qh_, const u16* __restrict__ Ql_,
    const u16* __restrict__ Kh_, const u16* __restrict__ Kl_,
    const u16* __restrict__ Vth_, const u16* __restrict__ Vtl_,
    u16* __restrict__ res_hi, u16* __restrict__ res_lo)
{
    __shared__ __align__(16) u16 KH[64 * 128], KL[64 * 128];   // [j][d], chunk-swizzled
    __shared__ __align__(16) u16 VH[128 * 64], VL[128 * 64];   // [d][n], chunk-swizzled
    __shared__ u16 Ph[8][16][72], Pl[8][16][72];               // per-wave private

    const int tid = threadIdx.x;
    const int l = tid & 63, w = tid >> 6;
    const int lm = l & 15, kg = l >> 4;
    const int bh = blockIdx.x;            // 0..63 (b*NH+h)
    const int qc = blockIdx.y;            // 0..7
    const int i = qc * 128 + w * 16 + lm; // this lane's q-row
    const size_t head = (size_t)bh * N_ * DK;

    // staging assignment: waves 0-1 KH, 2-3 KL, 4-5 VH, 6-7 VL (8 insts each)
    const u16* sgK = (w & 2) ? Kl_ : Kh_;
    const u16* sgV = (w & 2) ? Vtl_ : Vth_;
    u16* sdK = (w & 2) ? KL : KH;
    u16* sdV = (w & 2) ? VL : VH;
    const int sub0 = (w & 1) * 8;

    // Q fragments (B-operand): lane holds Q[i][kc*32 + kg*8 .. +7], hi/lo
    bfrag qfh[4], qfl[4];
    {
        const u16* qp = Qh_ + head + (size_t)i * DK + kg * 8;
        const u16* qp2 = Ql_ + head + (size_t)i * DK + kg * 8;
#pragma unroll
        for (int kc = 0; kc < 4; ++kc) {
            qfh[kc] = *(const bfrag*)(qp + kc * 32);
            qfl[kc] = *(const bfrag*)(qp2 + kc * 32);
        }
    }

    f4 acc_o[8] = {};
    float m_r = -3.0e38f, l_r = 0.f;

    for (int jt = 0; jt < 16; ++jt) {
        __syncthreads();   // prior iteration's K/V LDS reads complete
        if (w < 4) {
            // K tile: rows j 0..63, 16 chunks of 8 u16 per row; 4 rows/inst
#pragma unroll
            for (int u = 0; u < 8; ++u) {
                const int rbase = (sub0 + u) * 4;
                const int row = rbase + (l >> 4);
                GL2LDS(sgK + head + (size_t)(jt * 64 + row) * DK + (((l & 15) ^ (row & 7)) << 3),
                       sdK + rbase * 128);
            }
        } else {
            // Vt tile: rows d 0..127, 8 chunks per row; 8 rows/inst
#pragma unroll
            for (int u = 0; u < 8; ++u) {
                const int rbase = (sub0 + u) * 8;
                const int row = rbase + (l >> 3);
                GL2LDS(sgV + (size_t)bh * DK * N_ + (size_t)row * N_ + jt * 64
                           + (((l & 7) ^ (row & 7)) << 3),
                       sdV + rbase * 64);
            }
        }
        __syncthreads();   // staging landed (vmcnt(0) drained at barrier)

        // ---- S^T = K·Q^T over d=128 (split: KhQh + KhQl + KlQh) ----
        f4 sacc[4] = {};
#pragma unroll
        for (int kc = 0; kc < 4; ++kc) {
#pragma unroll
            for (int jf = 0; jf < 4; ++jf) {
                const int row = jf * 16 + lm;
                const int sw = (((kc << 2) | kg) ^ (lm & 7)) << 3;
                bfrag kh = *(const bfrag*)(KH + row * 128 + sw);
                bfrag kl = *(const bfrag*)(KL + row * 128 + sw);
                sacc[jf] = MFMA(kh, qfh[kc], sacc[jf]);
                sacc[jf] = MFMA(kh, qfl[kc], sacc[jf]);
                sacc[jf] = MFMA(kl, qfh[kc], sacc[jf]);
            }
        }

        // ---- online softmax: lane holds 16 logits of its own q-row ----
        float mt = sacc[0][0];
#pragma unroll
        for (int jf = 0; jf < 4; ++jf)
#pragma unroll
            for (int r = 0; r < 4; ++r) mt = fmaxf(mt, sacc[jf][r]);
        mt = fmaxf(mt, __shfl_xor(mt, 16));
        mt = fmaxf(mt, __shfl_xor(mt, 32));
        const float mn = fmaxf(m_r, mt);
        const float alpha = exp2f(m_r - mn);
        m_r = mn;

        float p[16];
        float rs = 0.f;
#pragma unroll
        for (int jf = 0; jf < 4; ++jf)
#pragma unroll
            for (int r = 0; r < 4; ++r) {
                float pv = exp2f(sacc[jf][r] - mn);
                p[jf * 4 + r] = pv;
                rs += pv;
            }
        rs += __shfl_xor(rs, 16);
        rs += __shfl_xor(rs, 32);
        l_r = l_r * alpha + rs;
#pragma unroll
        for (int df = 0; df < 8; ++df)
#pragma unroll
            for (int r = 0; r < 4; ++r) acc_o[df][r] *= alpha;

        // ---- P -> per-wave LDS (hi/lo) ----
#pragma unroll
        for (int jf = 0; jf < 4; ++jf) {
            u16 hb[4], lb[4];
#pragma unroll
            for (int r = 0; r < 4; ++r) {
                float pv = p[jf * 4 + r];
                hb[r] = f2bf(pv);
                lb[r] = f2bf(pv - bf2f(hb[r]));
            }
            *(uint2*)(void*)&Ph[w][lm][jf * 16 + kg * 4] =
                make_uint2((u32)hb[0] | ((u32)hb[1] << 16), (u32)hb[2] | ((u32)hb[3] << 16));
            *(uint2*)(void*)&Pl[w][lm][jf * 16 + kg * 4] =
                make_uint2((u32)lb[0] | ((u32)lb[1] << 16), (u32)lb[2] | ((u32)lb[3] << 16));
        }

        // ---- O^T += Vt · P  (split: VhPh + VhPl + VlPh), V from LDS ----
#pragma unroll
        for (int kc2 = 0; kc2 < 2; ++kc2) {
            bfrag pbh = *(const bfrag*)&Ph[w][lm][kc2 * 32 + kg * 8];
            bfrag pbl = *(const bfrag*)&Pl[w][lm][kc2 * 32 + kg * 8];
#pragma unroll
            for (int df = 0; df < 8; ++df) {
                const int row = df * 16 + lm;
                const int sw = (((kc2 << 2) | kg) ^ (lm & 7)) << 3;
                bfrag vh = *(const bfrag*)(VH + row * 64 + sw);
                bfrag vl = *(const bfrag*)(VL + row * 64 + sw);
                acc_o[df] = MFMA(vh, pbh, acc_o[df]);
                acc_o[df] = MFMA(vh, pbl, acc_o[df]);
                acc_o[df] = MFMA(vl, pbh, acc_o[df]);
            }
        }
    }

    // ---- epilogue: res[b][i][h*128+d] = O/l as bf16 hi/lo ----
    const float inv = 1.f / l_r;
    const int b = bh >> 2, h = bh & 3;
    const size_t ro = ((size_t)b * N_ + i) * C_ + h * DK;
#pragma unroll
    for (int df = 0; df < 8; ++df) {
        u16 hb[4], lb[4];
#pragma unroll
        for (int r = 0; r < 4; ++r) {
            float v = acc_o[df][r] * inv;
            hb[r] = f2bf(v);
            lb[r] = f2bf(v - bf2f(hb[r]));
        }
        const size_t o = ro + df * 16 + kg * 4;
        *(uint2*)(void*)(res_hi + o) = make_uint2((u32)hb[0] | ((u32)hb[1] << 16),
                                                  (u32)hb[2] | ((u32)hb[3] << 16));
        *(uint2*)(void*)(res_lo + o) = make_uint2((u32)lb[0] | ((u32)lb[1] << 16),
                                                  (u32)lb[2] | ((u32)lb[3] << 16));
    }
}

// ---------------------------------------------------------------------------
// Out projection, split-bf16 MFMA, computes outT[c'][n] directly. (+bias +x)
// ---------------------------------------------------------------------------
__global__ __launch_bounds__(256, 2) void out_mfma(
    const u16* __restrict__ woT_hi, const u16* __restrict__ woT_lo,
    const u16* __restrict__ res_hi, const u16* __restrict__ res_lo,
    const float* __restrict__ bo, const float* __restrict__ x,
    float* __restrict__ out)
{
    __shared__ __align__(16) u16 AH[128 * 64], AL[128 * 64], BH[128 * 64], BL[128 * 64];
    const int tid = threadIdx.x;
    const int l = tid & 63, w = tid >> 6;
    const int wr = w >> 1, wc = w & 1;
    const int lm = l & 15, kg = l >> 4;
    const int bx = blockIdx.x, by = blockIdx.y, b = blockIdx.z;
    const int c0 = bx * 128, n0 = by * 128;

    const u16* gsrc =
        (w == 0) ? woT_hi + (size_t)c0 * C_ :
        (w == 1) ? woT_lo + (size_t)c0 * C_ :
        (w == 2) ? res_hi + ((size_t)b * N_ + n0) * C_ :
                   res_lo + ((size_t)b * N_ + n0) * C_;
    u16* ldst = (w == 0) ? AH : (w == 1) ? AL : (w == 2) ? BH : BL;
    const int lane_off = (l >> 3) * C_ + (((l & 7) ^ (l >> 3)) << 3);

    f4 acc[4][4] = {};

    for (int it = 0; it < 8; ++it) {
        __syncthreads();
        const u16* g = gsrc + it * 64 + lane_off;
#pragma unroll
        for (int u = 0; u < 16; ++u)
            GL2LDS(g + (size_t)u * 8 * C_, ldst + u * 512);
        __syncthreads();

#pragma unroll
        for (int kk = 0; kk < 2; ++kk) {
            bfrag ah[4], al[4], bh[4], bl[4];
            const int s = ((kk * 4 + kg) ^ (lm & 7)) << 3;
#pragma unroll
            for (int f = 0; f < 4; ++f) {
                const int ar = wr * 64 + f * 16 + lm;
                const int br = wc * 64 + f * 16 + lm;
                ah[f] = *(const bfrag*)(AH + ar * 64 + s);
                al[f] = *(const bfrag*)(AL + ar * 64 + s);
                bh[f] = *(const bfrag*)(BH + br * 64 + s);
                bl[f] = *(const bfrag*)(BL + br * 64 + s);
            }
#pragma unroll
            for (int i = 0; i < 4; ++i)
#pragma unroll
                for (int j = 0; j < 4; ++j) {
                    acc[i][j] = MFMA(ah[i], bh[j], acc[i][j]);
                    acc[i][j] = MFMA(ah[i], bl[j], acc[i][j]);
                    acc[i][j] = MFMA(al[i], bh[j], acc[i][j]);
                }
        }
    }

#pragma unroll
    for (int j = 0; j < 4; ++j) {
        const int ncol = n0 + wc * 64 + j * 16 + lm;
#pragma unroll
        for (int i = 0; i < 4; ++i) {
#pragma unroll
            for (int r = 0; r < 4; ++r) {
                const int crow = c0 + wr * 64 + i * 16 + kg * 4 + r;
                const size_t o = ((size_t)b * C_ + crow) * N_ + ncol;
                out[o] = acc[i][j][r] + bo[crow] + x[o];
            }
        }
    }
}

extern "C" void kernel_launch(void* const* d_in, const int* in_sizes, int n_in,
                              void* d_out, int out_size, void* d_ws, size_t ws_size,
                              hipStream_t stream) {
    const float* x  = (const float*)d_in[0];
    const float* wp = (const float*)d_in[1];
    const float* bp = (const float*)d_in[2];
    const float* wo = (const float*)d_in[3];
    const float* bo = (const float*)d_in[4];
    float* out = (float*)d_out;

    // ws map (128 MiB). SEG = 8388608 elements.
    //  [0,32M):   xt hi/lo  -> res hi/lo after qkv
    //  [32M,64M): Q hi/lo   (-> woT hi/lo after attn)
    //  [64M,96M): K hi/lo
    //  [96M,128M): Vt hi/lo
    // d_out[0,3M): wpT hi/lo (dead before out_mfma overwrites with output)
    const size_t SEG = (size_t)B_ * N_ * C_;
    u16* xt_hi = (u16*)d_ws;
    u16* xt_lo = xt_hi + SEG;
    u16* Qh  = xt_hi + 2 * SEG;
    u16* Ql  = Qh + SEG;
    u16* Kh  = Ql + SEG;
    u16* Kl  = Kh + SEG;
    u16* Vth = Kl + SEG;
    u16* Vtl = Vth + SEG;
    u16* res_hi = xt_hi;
    u16* res_lo = xt_lo;
    u16* woT_hi = Qh;
    u16* woT_lo = woT_hi + C_ * C_;
    u16* wpT_hi = (u16*)d_out;
    u16* wpT_lo = wpT_hi + C_ * M3;

    conv_split_t<<<dim3(16, 8, 16), 256, 0, stream>>>(x, xt_hi, xt_lo, C_, N_);
    conv_split_t<<<dim3(24, 8, 1), 256, 0, stream>>>(wp, wpT_hi, wpT_lo, C_, M3);
    qkv_mfma<<<dim3(12, 8, 16), 256, 0, stream>>>(xt_hi, xt_lo, wpT_hi, wpT_lo, bp,
                                                  Qh, Ql, Kh, Kl, Vth, Vtl);
    attn_mfma<<<dim3(64, 8), 512, 0, stream>>>(Qh, Ql, Kh, Kl, Vth, Vtl, res_hi, res_lo);
    conv_split_t<<<dim3(8, 8, 1), 256, 0, stream>>>(wo, woT_hi, woT_lo, C_, C_);
    out_mfma<<<dim3(4, 8, 16), 256, 0, stream>>>(woT_hi, woT_lo, res_hi, res_lo, bo, x, out);
}

// Round 8
// 334.625 us; speedup vs baseline: 2.9748x; 1.0729x over previous
//
#include <hip/hip_runtime.h>

#define B_  16
#define C_  512
#define N_  1024
#define NH  4
#define DK  128
#define M3  1536   // 3*C

typedef unsigned short u16;
typedef unsigned int   u32;
typedef __attribute__((ext_vector_type(8))) short bfrag;   // 8 bf16 (4 VGPR)
typedef __attribute__((ext_vector_type(4))) float f4;      // MFMA C/D

#define MFMA(a, b, c) __builtin_amdgcn_mfma_f32_16x16x32_bf16(a, b, c, 0, 0, 0)

// async global->LDS, 16B per lane, lane l lands at lds_base + l*16
#define GL2LDS(gp, lp) __builtin_amdgcn_global_load_lds( \
    (__attribute__((address_space(1))) const unsigned int*)(const void*)(gp), \
    (__attribute__((address_space(3))) unsigned int*)(void*)(lp), 16, 0, 0)

__device__ __forceinline__ u16 f2bf(float f) {            // RNE fp32->bf16 (no NaN inputs)
    u32 u = __float_as_uint(f);
    return (u16)((u + 0x7FFFu + ((u >> 16) & 1u)) >> 16);
}
__device__ __forceinline__ float bf2f(u16 h) { return __uint_as_float(((u32)h) << 16); }

// dk^-0.5 * log2(e): folded into stored Q so attn uses exp2 directly
#define QSCL 0.12751741859316937f

// ---------------------------------------------------------------------------
// Convert: src fp32 [R][Cc] (batched via z) -> dst_hi/lo bf16 [Cc][R] (transpose+split)
// ---------------------------------------------------------------------------
__global__ __launch_bounds__(256) void conv_split_t(
    const float* __restrict__ src, u16* __restrict__ dhi, u16* __restrict__ dlo,
    int R, int Cc)
{
    __shared__ float Ts[64][65];
    const int tid = threadIdx.x;
    const int c0 = blockIdx.x * 64, r0 = blockIdx.y * 64;
    const size_t bofs = (size_t)blockIdx.z * R * Cc;

#pragma unroll
    for (int p = 0; p < 4; ++p) {
        int r = p * 16 + (tid >> 4);
        int c = (tid & 15) * 4;
        float4 v = *(const float4*)(src + bofs + (size_t)(r0 + r) * Cc + c0 + c);
        Ts[c + 0][r] = v.x; Ts[c + 1][r] = v.y; Ts[c + 2][r] = v.z; Ts[c + 3][r] = v.w;
    }
    __syncthreads();
#pragma unroll
    for (int p = 0; p < 4; ++p) {
        int cc = p * 16 + (tid >> 4);
        int rr = (tid & 15) * 4;
        float f0 = Ts[cc][rr + 0], f1 = Ts[cc][rr + 1];
        float f2 = Ts[cc][rr + 2], f3 = Ts[cc][rr + 3];
        u16 h0 = f2bf(f0), h1 = f2bf(f1), h2 = f2bf(f2), h3 = f2bf(f3);
        u16 l0 = f2bf(f0 - bf2f(h0)), l1 = f2bf(f1 - bf2f(h1));
        u16 l2 = f2bf(f2 - bf2f(h2)), l3 = f2bf(f3 - bf2f(h3));
        size_t o = bofs + (size_t)(c0 + cc) * R + r0 + rr;
        *(uint2*)(void*)(dhi + o) = make_uint2((u32)h0 | ((u32)h1 << 16), (u32)h2 | ((u32)h3 << 16));
        *(uint2*)(void*)(dlo + o) = make_uint2((u32)l0 | ((u32)l1 << 16), (u32)l2 | ((u32)l3 << 16));
    }
}

// ---------------------------------------------------------------------------
// QKV projection, split-bf16 MFMA. Epilogue writes attention-ready operands:
//   Q hi/lo [b][h][n][d] (prescaled by dk^-0.5*log2e), K hi/lo [b][h][n][d],
//   Vt hi/lo [b][h][d][n] (transposed for PV A-operand)
// ---------------------------------------------------------------------------
__global__ __launch_bounds__(256, 2) void qkv_mfma(
    const u16* __restrict__ xt_hi, const u16* __restrict__ xt_lo,
    const u16* __restrict__ wpT_hi, const u16* __restrict__ wpT_lo,
    const float* __restrict__ bp,
    u16* __restrict__ Qh, u16* __restrict__ Ql,
    u16* __restrict__ Kh, u16* __restrict__ Kl,
    u16* __restrict__ Vth, u16* __restrict__ Vtl)
{
    __shared__ __align__(16) u16 AH[128 * 64], AL[128 * 64], BH[128 * 64], BL[128 * 64];
    const int tid = threadIdx.x;
    const int l = tid & 63, w = tid >> 6;
    const int wr = w >> 1, wc = w & 1;
    const int lm = l & 15, kg = l >> 4;
    const int bx = blockIdx.x, by = blockIdx.y, b = blockIdx.z;
    const int m0 = bx * 128, n0 = by * 128;

    const u16* gsrc =
        (w == 0) ? xt_hi + ((size_t)b * N_ + n0) * C_ :
        (w == 1) ? xt_lo + ((size_t)b * N_ + n0) * C_ :
        (w == 2) ? wpT_hi + (size_t)m0 * C_ :
                   wpT_lo + (size_t)m0 * C_;
    u16* ldst = (w == 0) ? AH : (w == 1) ? AL : (w == 2) ? BH : BL;
    const int lane_off = (l >> 3) * C_ + (((l & 7) ^ (l >> 3)) << 3);

    f4 acc[4][4] = {};

    for (int it = 0; it < 8; ++it) {
        __syncthreads();
        const u16* g = gsrc + it * 64 + lane_off;
#pragma unroll
        for (int u = 0; u < 16; ++u)
            GL2LDS(g + (size_t)u * 8 * C_, ldst + u * 512);
        __syncthreads();

#pragma unroll
        for (int kk = 0; kk < 2; ++kk) {
            bfrag ah[4], al[4], bh[4], bl[4];
            const int s = ((kk * 4 + kg) ^ (lm & 7)) << 3;
#pragma unroll
            for (int f = 0; f < 4; ++f) {
                const int ar = wr * 64 + f * 16 + lm;
                const int br = wc * 64 + f * 16 + lm;
                ah[f] = *(const bfrag*)(AH + ar * 64 + s);
                al[f] = *(const bfrag*)(AL + ar * 64 + s);
                bh[f] = *(const bfrag*)(BH + br * 64 + s);
                bl[f] = *(const bfrag*)(BL + br * 64 + s);
            }
#pragma unroll
            for (int i = 0; i < 4; ++i)
#pragma unroll
                for (int j = 0; j < 4; ++j) {
                    acc[i][j] = MFMA(ah[i], bh[j], acc[i][j]);
                    acc[i][j] = MFMA(ah[i], bl[j], acc[i][j]);
                    acc[i][j] = MFMA(al[i], bh[j], acc[i][j]);
                }
        }
    }

    const int hh = bx / 3, t = bx - hh * 3;
#pragma unroll
    for (int j = 0; j < 4; ++j) {
        const int mcol = m0 + wc * 64 + j * 16 + lm;
        const float bias = bp[mcol];
        const int d = mcol & 127;
#pragma unroll
        for (int i = 0; i < 4; ++i) {
            const int tok = n0 + wr * 64 + i * 16 + kg * 4;
            if (t == 2) {
                u16 hb[4], lb[4];
#pragma unroll
                for (int r = 0; r < 4; ++r) {
                    float v = acc[i][j][r] + bias;
                    hb[r] = f2bf(v);
                    lb[r] = f2bf(v - bf2f(hb[r]));
                }
                const size_t o = ((size_t)(b * NH + hh) * DK + d) * N_ + tok;
                *(uint2*)(void*)(Vth + o) = make_uint2((u32)hb[0] | ((u32)hb[1] << 16),
                                                       (u32)hb[2] | ((u32)hb[3] << 16));
                *(uint2*)(void*)(Vtl + o) = make_uint2((u32)lb[0] | ((u32)lb[1] << 16),
                                                       (u32)lb[2] | ((u32)lb[3] << 16));
            } else {
                u16* dh = (t == 0) ? Qh : Kh;
                u16* dl = (t == 0) ? Ql : Kl;
                const size_t o = ((size_t)(b * NH + hh) * N_ + tok) * DK + d;
#pragma unroll
                for (int r = 0; r < 4; ++r) {
                    float v = acc[i][j][r] + bias;
                    if (t == 0) v *= QSCL;
                    u16 hb = f2bf(v);
                    dh[o + (size_t)r * DK] = hb;
                    dl[o + (size_t)r * DK] = f2bf(v - bf2f(hb));
                }
            }
        }
    }
}

// ---------------------------------------------------------------------------
// Flash attention, split-bf16 MFMA, swapped operands (S^T = K·Q^T).
// 512 threads = 8 waves; wave owns TWO 16-row q-sets (i, i+128) so every
// K/V LDS fragment read feeds 6 MFMAs (3 split-products x 2 sets) --
// halves the LDS-read traffic per unit work vs round-5 (which was
// LDS-throughput-bound at MfmaUtil 29%). Block covers 256 q-rows ->
// grid 64x4 = 256 blocks = 1 block/CU, single round.
// LDS: K 32K + V 32K + P 72K = 136 KB -> 1 block/CU.
// ---------------------------------------------------------------------------
__global__ __launch_bounds__(512, 2) void attn_mfma(
    const u16* __restrict__ Qh_, const u16* __restrict__ Ql_,
    const u16* __restrict__ Kh_, const u16* __restrict__ Kl_,
    const u16* __restrict__ Vth_, const u16* __restrict__ Vtl_,
    u16* __restrict__ res_hi, u16* __restrict__ res_lo)
{
    __shared__ __align__(16) u16 KH[64 * 128], KL[64 * 128];   // [j][d], chunk-swizzled
    __shared__ __align__(16) u16 VH[128 * 64], VL[128 * 64];   // [d][n], chunk-swizzled
    __shared__ u16 Ph[8][2][16][72], Pl[8][2][16][72];         // per-wave, per-set

    const int tid = threadIdx.x;
    const int l = tid & 63, w = tid >> 6;
    const int lm = l & 15, kg = l >> 4;
    const int bh = blockIdx.x;            // 0..63 (b*NH+h)
    const int qc = blockIdx.y;            // 0..3
    const int i0s = qc * 256 + w * 16 + lm;   // set0 q-row; set1 = +128
    const size_t head = (size_t)bh * N_ * DK;

    // staging assignment: waves 0-1 KH, 2-3 KL, 4-5 VH, 6-7 VL (8 insts each)
    const u16* sgK = (w & 2) ? Kl_ : Kh_;
    const u16* sgV = (w & 2) ? Vtl_ : Vth_;
    u16* sdK = (w & 2) ? KL : KH;
    u16* sdV = (w & 2) ? VL : VH;
    const int sub0 = (w & 1) * 8;

    // Q fragments (B-operand), both sets: lane holds Q[i_s][kc*32 + kg*8 .. +7]
    bfrag qfh[2][4], qfl[2][4];
#pragma unroll
    for (int s = 0; s < 2; ++s) {
        const u16* qp  = Qh_ + head + (size_t)(i0s + s * 128) * DK + kg * 8;
        const u16* qp2 = Ql_ + head + (size_t)(i0s + s * 128) * DK + kg * 8;
#pragma unroll
        for (int kc = 0; kc < 4; ++kc) {
            qfh[s][kc] = *(const bfrag*)(qp + kc * 32);
            qfl[s][kc] = *(const bfrag*)(qp2 + kc * 32);
        }
    }

    f4 acc_o[2][8] = {};
    float m_r[2] = {-3.0e38f, -3.0e38f}, l_r[2] = {0.f, 0.f};

    for (int jt = 0; jt < 16; ++jt) {
        __syncthreads();   // prior iteration's K/V LDS reads complete
        if (w < 4) {
#pragma unroll
            for (int u = 0; u < 8; ++u) {
                const int rbase = (sub0 + u) * 4;
                const int row = rbase + (l >> 4);
                GL2LDS(sgK + head + (size_t)(jt * 64 + row) * DK + (((l & 15) ^ (row & 7)) << 3),
                       sdK + rbase * 128);
            }
        } else {
#pragma unroll
            for (int u = 0; u < 8; ++u) {
                const int rbase = (sub0 + u) * 8;
                const int row = rbase + (l >> 3);
                GL2LDS(sgV + (size_t)bh * DK * N_ + (size_t)row * N_ + jt * 64
                           + (((l & 7) ^ (row & 7)) << 3),
                       sdV + rbase * 64);
            }
        }
        __syncthreads();   // staging landed (vmcnt(0) drained at barrier)

        // ---- S^T = K·Q^T, both q-sets share each K fragment ----
        f4 sacc[2][4] = {};
#pragma unroll
        for (int kc = 0; kc < 4; ++kc) {
#pragma unroll
            for (int jf = 0; jf < 4; ++jf) {
                const int row = jf * 16 + lm;
                const int sw = (((kc << 2) | kg) ^ (lm & 7)) << 3;
                bfrag kh = *(const bfrag*)(KH + row * 128 + sw);
                bfrag kl = *(const bfrag*)(KL + row * 128 + sw);
#pragma unroll
                for (int s = 0; s < 2; ++s) {
                    sacc[s][jf] = MFMA(kh, qfh[s][kc], sacc[s][jf]);
                    sacc[s][jf] = MFMA(kh, qfl[s][kc], sacc[s][jf]);
                    sacc[s][jf] = MFMA(kl, qfh[s][kc], sacc[s][jf]);
                }
            }
        }

        // ---- online softmax + P->LDS, per set ----
#pragma unroll
        for (int s = 0; s < 2; ++s) {
            float mt = sacc[s][0][0];
#pragma unroll
            for (int jf = 0; jf < 4; ++jf)
#pragma unroll
                for (int r = 0; r < 4; ++r) mt = fmaxf(mt, sacc[s][jf][r]);
            mt = fmaxf(mt, __shfl_xor(mt, 16));
            mt = fmaxf(mt, __shfl_xor(mt, 32));
            const float mn = fmaxf(m_r[s], mt);
            const float alpha = exp2f(m_r[s] - mn);
            m_r[s] = mn;

            float rs = 0.f;
#pragma unroll
            for (int jf = 0; jf < 4; ++jf) {
                u16 hb[4], lb[4];
#pragma unroll
                for (int r = 0; r < 4; ++r) {
                    float pv = exp2f(sacc[s][jf][r] - mn);
                    rs += pv;
                    hb[r] = f2bf(pv);
                    lb[r] = f2bf(pv - bf2f(hb[r]));
                }
                *(uint2*)(void*)&Ph[w][s][lm][jf * 16 + kg * 4] =
                    make_uint2((u32)hb[0] | ((u32)hb[1] << 16), (u32)hb[2] | ((u32)hb[3] << 16));
                *(uint2*)(void*)&Pl[w][s][lm][jf * 16 + kg * 4] =
                    make_uint2((u32)lb[0] | ((u32)lb[1] << 16), (u32)lb[2] | ((u32)lb[3] << 16));
            }
            rs += __shfl_xor(rs, 16);
            rs += __shfl_xor(rs, 32);
            l_r[s] = l_r[s] * alpha + rs;
#pragma unroll
            for (int df = 0; df < 8; ++df)
#pragma unroll
                for (int r = 0; r < 4; ++r) acc_o[s][df][r] *= alpha;
        }

        // ---- O^T += Vt · P, both P-sets share each V fragment ----
#pragma unroll
        for (int kc2 = 0; kc2 < 2; ++kc2) {
            bfrag pbh0 = *(const bfrag*)&Ph[w][0][lm][kc2 * 32 + kg * 8];
            bfrag pbl0 = *(const bfrag*)&Pl[w][0][lm][kc2 * 32 + kg * 8];
            bfrag pbh1 = *(const bfrag*)&Ph[w][1][lm][kc2 * 32 + kg * 8];
            bfrag pbl1 = *(const bfrag*)&Pl[w][1][lm][kc2 * 32 + kg * 8];
#pragma unroll
            for (int df = 0; df < 8; ++df) {
                const int row = df * 16 + lm;
                const int sw = (((kc2 << 2) | kg) ^ (lm & 7)) << 3;
                bfrag vh = *(const bfrag*)(VH + row * 64 + sw);
                bfrag vl = *(const bfrag*)(VL + row * 64 + sw);
                acc_o[0][df] = MFMA(vh, pbh0, acc_o[0][df]);
                acc_o[0][df] = MFMA(vh, pbl0, acc_o[0][df]);
                acc_o[0][df] = MFMA(vl, pbh0, acc_o[0][df]);
                acc_o[1][df] = MFMA(vh, pbh1, acc_o[1][df]);
                acc_o[1][df] = MFMA(vh, pbl1, acc_o[1][df]);
                acc_o[1][df] = MFMA(vl, pbh1, acc_o[1][df]);
            }
        }
    }

    // ---- epilogue: res[b][i][h*128+d] = O/l as bf16 hi/lo, both sets ----
    const int b = bh >> 2, h = bh & 3;
#pragma unroll
    for (int s = 0; s < 2; ++s) {
        const float inv = 1.f / l_r[s];
        const size_t ro = ((size_t)b * N_ + i0s + s * 128) * C_ + h * DK;
#pragma unroll
        for (int df = 0; df < 8; ++df) {
            u16 hb[4], lb[4];
#pragma unroll
            for (int r = 0; r < 4; ++r) {
                float v = acc_o[s][df][r] * inv;
                hb[r] = f2bf(v);
                lb[r] = f2bf(v - bf2f(hb[r]));
            }
            const size_t o = ro + df * 16 + kg * 4;
            *(uint2*)(void*)(res_hi + o) = make_uint2((u32)hb[0] | ((u32)hb[1] << 16),
                                                      (u32)hb[2] | ((u32)hb[3] << 16));
            *(uint2*)(void*)(res_lo + o) = make_uint2((u32)lb[0] | ((u32)lb[1] << 16),
                                                      (u32)lb[2] | ((u32)lb[3] << 16));
        }
    }
}

// ---------------------------------------------------------------------------
// Out projection, split-bf16 MFMA, computes outT[c'][n] directly. (+bias +x)
// ---------------------------------------------------------------------------
__global__ __launch_bounds__(256, 2) void out_mfma(
    const u16* __restrict__ woT_hi, const u16* __restrict__ woT_lo,
    const u16* __restrict__ res_hi, const u16* __restrict__ res_lo,
    const float* __restrict__ bo, const float* __restrict__ x,
    float* __restrict__ out)
{
    __shared__ __align__(16) u16 AH[128 * 64], AL[128 * 64], BH[128 * 64], BL[128 * 64];
    const int tid = threadIdx.x;
    const int l = tid & 63, w = tid >> 6;
    const int wr = w >> 1, wc = w & 1;
    const int lm = l & 15, kg = l >> 4;
    const int bx = blockIdx.x, by = blockIdx.y, b = blockIdx.z;
    const int c0 = bx * 128, n0 = by * 128;

    const u16* gsrc =
        (w == 0) ? woT_hi + (size_t)c0 * C_ :
        (w == 1) ? woT_lo + (size_t)c0 * C_ :
        (w == 2) ? res_hi + ((size_t)b * N_ + n0) * C_ :
                   res_lo + ((size_t)b * N_ + n0) * C_;
    u16* ldst = (w == 0) ? AH : (w == 1) ? AL : (w == 2) ? BH : BL;
    const int lane_off = (l >> 3) * C_ + (((l & 7) ^ (l >> 3)) << 3);

    f4 acc[4][4] = {};

    for (int it = 0; it < 8; ++it) {
        __syncthreads();
        const u16* g = gsrc + it * 64 + lane_off;
#pragma unroll
        for (int u = 0; u < 16; ++u)
            GL2LDS(g + (size_t)u * 8 * C_, ldst + u * 512);
        __syncthreads();

#pragma unroll
        for (int kk = 0; kk < 2; ++kk) {
            bfrag ah[4], al[4], bh[4], bl[4];
            const int s = ((kk * 4 + kg) ^ (lm & 7)) << 3;
#pragma unroll
            for (int f = 0; f < 4; ++f) {
                const int ar = wr * 64 + f * 16 + lm;
                const int br = wc * 64 + f * 16 + lm;
                ah[f] = *(const bfrag*)(AH + ar * 64 + s);
                al[f] = *(const bfrag*)(AL + ar * 64 + s);
                bh[f] = *(const bfrag*)(BH + br * 64 + s);
                bl[f] = *(const bfrag*)(BL + br * 64 + s);
            }
#pragma unroll
            for (int i = 0; i < 4; ++i)
#pragma unroll
                for (int j = 0; j < 4; ++j) {
                    acc[i][j] = MFMA(ah[i], bh[j], acc[i][j]);
                    acc[i][j] = MFMA(ah[i], bl[j], acc[i][j]);
                    acc[i][j] = MFMA(al[i], bh[j], acc[i][j]);
                }
        }
    }

#pragma unroll
    for (int j = 0; j < 4; ++j) {
        const int ncol = n0 + wc * 64 + j * 16 + lm;
#pragma unroll
        for (int i = 0; i < 4; ++i) {
#pragma unroll
            for (int r = 0; r < 4; ++r) {
                const int crow = c0 + wr * 64 + i * 16 + kg * 4 + r;
                const size_t o = ((size_t)b * C_ + crow) * N_ + ncol;
                out[o] = acc[i][j][r] + bo[crow] + x[o];
            }
        }
    }
}

extern "C" void kernel_launch(void* const* d_in, const int* in_sizes, int n_in,
                              void* d_out, int out_size, void* d_ws, size_t ws_size,
                              hipStream_t stream) {
    const float* x  = (const float*)d_in[0];
    const float* wp = (const float*)d_in[1];
    const float* bp = (const float*)d_in[2];
    const float* wo = (const float*)d_in[3];
    const float* bo = (const float*)d_in[4];
    float* out = (float*)d_out;

    // ws map (128 MiB). SEG = 8388608 elements.
    //  [0,32M):   xt hi/lo  -> res hi/lo after qkv
    //  [32M,64M): Q hi/lo   (-> woT hi/lo after attn)
    //  [64M,96M): K hi/lo
    //  [96M,128M): Vt hi/lo
    // d_out[0,3M): wpT hi/lo (dead before out_mfma overwrites with output)
    const size_t SEG = (size_t)B_ * N_ * C_;
    u16* xt_hi = (u16*)d_ws;
    u16* xt_lo = xt_hi + SEG;
    u16* Qh  = xt_hi + 2 * SEG;
    u16* Ql  = Qh + SEG;
    u16* Kh  = Ql + SEG;
    u16* Kl  = Kh + SEG;
    u16* Vth = Kl + SEG;
    u16* Vtl = Vth + SEG;
    u16* res_hi = xt_hi;
    u16* res_lo = xt_lo;
    u16* woT_hi = Qh;
    u16* woT_lo = woT_hi + C_ * C_;
    u16* wpT_hi = (u16*)d_out;
    u16* wpT_lo = wpT_hi + C_ * M3;

    conv_split_t<<<dim3(16, 8, 16), 256, 0, stream>>>(x, xt_hi, xt_lo, C_, N_);
    conv_split_t<<<dim3(24, 8, 1), 256, 0, stream>>>(wp, wpT_hi, wpT_lo, C_, M3);
    qkv_mfma<<<dim3(12, 8, 16), 256, 0, stream>>>(xt_hi, xt_lo, wpT_hi, wpT_lo, bp,
                                                  Qh, Ql, Kh, Kl, Vth, Vtl);
    attn_mfma<<<dim3(64, 4), 512, 0, stream>>>(Qh, Ql, Kh, Kl, Vth, Vtl, res_hi, res_lo);
    conv_split_t<<<dim3(8, 8, 1), 256, 0, stream>>>(wo, woT_hi, woT_lo, C_, C_);
    out_mfma<<<dim3(4, 8, 16), 256, 0, stream>>>(woT_hi, woT_lo, res_hi, res_lo, bo, x, out);
}